// Round 1
// baseline (1024.195 us; speedup 1.0000x reference)
//
#include <hip/hip_runtime.h>

// ---------------- problem dims (fixed by reference) ----------------
// N=50000, E=640000, DIN=128, DH=256, DOUT=128

// ================= CSR build =================
__global__ void hist_kernel(const int* __restrict__ dst, int* __restrict__ cnt, int E) {
    int i = blockIdx.x * blockDim.x + threadIdx.x;
    if (i < E) atomicAdd(&cnt[dst[i]], 1);
}

__global__ __launch_bounds__(1024) void scan_kernel(const int* __restrict__ cnt,
                                                    int* __restrict__ rowptr,
                                                    int* __restrict__ cursor,
                                                    float* __restrict__ invdeg, int N) {
    __shared__ int part[1024];
    int t = threadIdx.x;
    int chunk = (N + 1023) >> 10;
    int s = t * chunk;
    int e = s + chunk; if (e > N) e = N;
    int sum = 0;
    for (int i = s; i < e; i++) sum += cnt[i];
    part[t] = sum;
    __syncthreads();
    // inclusive Hillis-Steele scan over 1024 partials
    for (int off = 1; off < 1024; off <<= 1) {
        int v = 0;
        if (t >= off) v = part[t - off];
        __syncthreads();
        part[t] += v;
        __syncthreads();
    }
    int run = part[t] - sum;  // exclusive base
    for (int i = s; i < e; i++) {
        rowptr[i] = run;
        cursor[i] = run;
        int c = cnt[i];
        invdeg[i] = 1.0f / (float)(c > 1 ? c : 1);
        run += c;
    }
    if (t == 1023) rowptr[N] = part[1023];
}

__global__ void scatter_kernel(const int* __restrict__ src, const int* __restrict__ dst,
                               int* __restrict__ cursor, int* __restrict__ col, int E) {
    int i = blockIdx.x * blockDim.x + threadIdx.x;
    if (i < E) {
        int p = atomicAdd(&cursor[dst[i]], 1);
        col[p] = src[i];
    }
}

// ================= CSR mean aggregation =================
// one wave (64 lanes) per destination node
__global__ __launch_bounds__(256) void agg_mean_128(const int* __restrict__ rowptr,
                                                    const int* __restrict__ col,
                                                    const float* __restrict__ invdeg,
                                                    const float* __restrict__ X,
                                                    const float* __restrict__ addend,
                                                    float* __restrict__ out, int N) {
    int wid = (blockIdx.x * blockDim.x + threadIdx.x) >> 6;
    int lane = threadIdx.x & 63;
    if (wid >= N) return;
    int s = rowptr[wid], e = rowptr[wid + 1];
    float2 acc = {0.f, 0.f};
    for (int j = s; j < e; j++) {
        int c = col[j];
        float2 v = *(const float2*)(X + (size_t)c * 128 + lane * 2);
        acc.x += v.x; acc.y += v.y;
    }
    float inv = invdeg[wid];
    float2 o; o.x = acc.x * inv; o.y = acc.y * inv;
    if (addend) {
        float2 a = *(const float2*)(addend + (size_t)wid * 128 + lane * 2);
        o.x += a.x; o.y += a.y;
    }
    *(float2*)(out + (size_t)wid * 128 + lane * 2) = o;
}

__global__ __launch_bounds__(256) void agg_mean_256(const int* __restrict__ rowptr,
                                                    const int* __restrict__ col,
                                                    const float* __restrict__ invdeg,
                                                    const float* __restrict__ X,
                                                    float* __restrict__ out, int N) {
    int wid = (blockIdx.x * blockDim.x + threadIdx.x) >> 6;
    int lane = threadIdx.x & 63;
    if (wid >= N) return;
    int s = rowptr[wid], e = rowptr[wid + 1];
    float4 acc = {0.f, 0.f, 0.f, 0.f};
    for (int j = s; j < e; j++) {
        int c = col[j];
        float4 v = *(const float4*)(X + (size_t)c * 256 + lane * 4);
        acc.x += v.x; acc.y += v.y; acc.z += v.z; acc.w += v.w;
    }
    float inv = invdeg[wid];
    float4 o; o.x = acc.x * inv; o.y = acc.y * inv; o.z = acc.z * inv; o.w = acc.w * inv;
    *(float4*)(out + (size_t)wid * 256 + lane * 4) = o;
}

// ================= dual GEMM: C = A1@W1 + A2@W2 + bias =================
// A row-major [M,K], W row-major [K,Nc]. K1,K2 multiples of 16; Nc multiple of 64.
#define BM 64
#define BN 64
#define BK 16

__global__ __launch_bounds__(256) void gemm_dual(const float* __restrict__ A1, int K1,
                                                 const float* __restrict__ W1,
                                                 const float* __restrict__ A2, int K2,
                                                 const float* __restrict__ W2,
                                                 const float* __restrict__ bias,
                                                 float* __restrict__ C, int M, int Nc) {
    __shared__ float sA[BK][BM + 4];  // k-major; +4 keeps float4 alignment, breaks pow2 stride
    __shared__ float sB[BK][BN + 4];
    int t = threadIdx.x;
    int bm = blockIdx.x * BM;
    int bn = blockIdx.y * BN;
    int tm = (t >> 4) << 2;  // 0..60
    int tn = (t & 15) << 2;  // 0..60
    float acc[4][4] = {};
    // loader indices
    int lr = t >> 2;          // A: row in tile 0..63
    int lk4 = (t & 3) << 2;   // A: k vec start
    int lbk = t >> 4;         // B: k row 0..15
    int lbn = (t & 15) << 2;  // B: col vec start

    int ktotal = K1 + K2;
    for (int k0 = 0; k0 < ktotal; k0 += BK) {
        const float* Ap; const float* Wp; int Kld; int kk0;
        if (k0 < K1) { Ap = A1; Wp = W1; Kld = K1; kk0 = k0; }
        else         { Ap = A2; Wp = W2; Kld = K2; kk0 = k0 - K1; }
        {   // A tile -> sA[k][m]
            int row = bm + lr;
            float4 v = {0.f, 0.f, 0.f, 0.f};
            if (row < M) v = *(const float4*)(Ap + (size_t)row * Kld + kk0 + lk4);
            sA[lk4 + 0][lr] = v.x;
            sA[lk4 + 1][lr] = v.y;
            sA[lk4 + 2][lr] = v.z;
            sA[lk4 + 3][lr] = v.w;
        }
        {   // W tile -> sB[k][n]
            float4 v = *(const float4*)(Wp + (size_t)(kk0 + lbk) * Nc + bn + lbn);
            *(float4*)&sB[lbk][lbn] = v;
        }
        __syncthreads();
#pragma unroll
        for (int kk = 0; kk < BK; kk++) {
            float4 a = *(const float4*)&sA[kk][tm];
            float4 b = *(const float4*)&sB[kk][tn];
            float av[4] = {a.x, a.y, a.z, a.w};
            float bv[4] = {b.x, b.y, b.z, b.w};
#pragma unroll
            for (int i = 0; i < 4; i++)
#pragma unroll
                for (int j = 0; j < 4; j++) acc[i][j] += av[i] * bv[j];
        }
        __syncthreads();
    }
    float bq[4] = {0.f, 0.f, 0.f, 0.f};
    if (bias) {
        float4 bb = *(const float4*)(bias + bn + tn);
        bq[0] = bb.x; bq[1] = bb.y; bq[2] = bb.z; bq[3] = bb.w;
    }
#pragma unroll
    for (int i = 0; i < 4; i++) {
        int row = bm + tm + i;
        if (row < M) {
            float4 o;
            o.x = acc[i][0] + bq[0];
            o.y = acc[i][1] + bq[1];
            o.z = acc[i][2] + bq[2];
            o.w = acc[i][3] + bq[3];
            *(float4*)(C + (size_t)row * Nc + bn + tn) = o;
        }
    }
}

// ================= LayerNorm(256) + ReLU + add =================
// one wave per row: out = relu(LN(u)*g+b) + addv
__global__ __launch_bounds__(256) void ln_relu_add(const float* __restrict__ u,
                                                   const float* __restrict__ addv,
                                                   const float* __restrict__ g,
                                                   const float* __restrict__ b,
                                                   float* __restrict__ out, int N) {
    int row = (blockIdx.x * blockDim.x + threadIdx.x) >> 6;
    int lane = threadIdx.x & 63;
    if (row >= N) return;
    float4 v = *(const float4*)(u + (size_t)row * 256 + lane * 4);
    float s = v.x + v.y + v.z + v.w;
    float sq = v.x * v.x + v.y * v.y + v.z * v.z + v.w * v.w;
    for (int off = 1; off < 64; off <<= 1) {
        s += __shfl_xor(s, off, 64);
        sq += __shfl_xor(sq, off, 64);
    }
    float mu = s * (1.f / 256.f);
    float var = sq * (1.f / 256.f) - mu * mu;
    float rs = rsqrtf(var + 1e-5f);
    float4 gv = *(const float4*)(g + lane * 4);
    float4 bv = *(const float4*)(b + lane * 4);
    float4 av = *(const float4*)(addv + (size_t)row * 256 + lane * 4);
    float4 o;
    o.x = fmaxf((v.x - mu) * rs * gv.x + bv.x, 0.f) + av.x;
    o.y = fmaxf((v.y - mu) * rs * gv.y + bv.y, 0.f) + av.y;
    o.z = fmaxf((v.z - mu) * rs * gv.z + bv.z, 0.f) + av.z;
    o.w = fmaxf((v.w - mu) * rs * gv.w + bv.w, 0.f) + av.w;
    *(float4*)(out + (size_t)row * 256 + lane * 4) = o;
}

// ================= launch =================
extern "C" void kernel_launch(void* const* d_in, const int* in_sizes, int n_in,
                              void* d_out, int out_size, void* d_ws, size_t ws_size,
                              hipStream_t stream) {
    const float* x   = (const float*)d_in[0];
    const int*   ei  = (const int*)d_in[1];
    const float* W1l = (const float*)d_in[2];
    const float* b1l = (const float*)d_in[3];
    const float* W1r = (const float*)d_in[4];
    const float* g1  = (const float*)d_in[5];
    const float* be1 = (const float*)d_in[6];
    const float* Wsk = (const float*)d_in[7];
    const float* bsk = (const float*)d_in[8];
    const float* W2l = (const float*)d_in[9];
    const float* b2l = (const float*)d_in[10];
    const float* W2r = (const float*)d_in[11];
    const float* g2  = (const float*)d_in[12];
    const float* be2 = (const float*)d_in[13];
    const float* W3l = (const float*)d_in[14];
    const float* b3l = (const float*)d_in[15];
    const float* W3r = (const float*)d_in[16];

    const int N = in_sizes[0] / 128;
    const int E = in_sizes[1] / 2;
    const int* src = ei;
    const int* dst = ei + E;

    // workspace layout
    char* p = (char*)d_ws;
    auto alloc = [&](size_t bytes) {
        void* r = (void*)p;
        p += (bytes + 255) & ~(size_t)255;
        return r;
    };
    int*   cnt     = (int*)alloc(sizeof(int) * N);
    int*   rowptr  = (int*)alloc(sizeof(int) * (N + 1));
    int*   cursor  = (int*)alloc(sizeof(int) * N);
    float* invdeg  = (float*)alloc(sizeof(float) * N);
    int*   col     = (int*)alloc(sizeof(int) * E);
    float* bufA128 = (float*)alloc(sizeof(float) * (size_t)N * 128);  // aggX, later t3
    float* bufB128 = (float*)alloc(sizeof(float) * (size_t)N * 128);  // r3
    float* bufU    = (float*)alloc(sizeof(float) * (size_t)N * 256);  // u1, agg2, h2
    float* bufS    = (float*)alloc(sizeof(float) * (size_t)N * 256);  // s, u2
    float* bufH    = (float*)alloc(sizeof(float) * (size_t)N * 256);  // h

    // ---- CSR build (reused by all 3 aggregations) ----
    hipMemsetAsync(cnt, 0, sizeof(int) * N, stream);
    hist_kernel<<<(E + 255) / 256, 256, 0, stream>>>(dst, cnt, E);
    scan_kernel<<<1, 1024, 0, stream>>>(cnt, rowptr, cursor, invdeg, N);
    scatter_kernel<<<(E + 255) / 256, 256, 0, stream>>>(src, dst, cursor, col, E);

    int aggBlocks = (N + 3) / 4;  // 4 waves per 256-thread block, 1 wave/node

    // ---- layer 1 ----
    // aggX = mean-agg(x)  [N,128]
    agg_mean_128<<<aggBlocks, 256, 0, stream>>>(rowptr, col, invdeg, x, nullptr, bufA128, N);
    // u1 = aggX@W1l + x@W1r + b1l  [N,256]
    {
        dim3 g((N + BM - 1) / BM, 256 / BN);
        gemm_dual<<<g, 256, 0, stream>>>(bufA128, 128, W1l, x, 128, W1r, b1l, bufU, N, 256);
    }
    // s = x@Wsk + bsk  [N,256]
    {
        dim3 g((N + BM - 1) / BM, 256 / BN);
        gemm_dual<<<g, 256, 0, stream>>>(x, 128, Wsk, nullptr, 0, nullptr, bsk, bufS, N, 256);
    }
    // h = relu(LN(u1)) + s
    ln_relu_add<<<aggBlocks, 256, 0, stream>>>(bufU, bufS, g1, be1, bufH, N);

    // ---- layer 2 ----
    // agg2 = mean-agg(h) [N,256]  (bufU dead -> reuse)
    agg_mean_256<<<aggBlocks, 256, 0, stream>>>(rowptr, col, invdeg, bufH, bufU, N);
    // u2 = agg2@W2l + h@W2r + b2l (bufS dead -> reuse)
    {
        dim3 g((N + BM - 1) / BM, 256 / BN);
        gemm_dual<<<g, 256, 0, stream>>>(bufU, 256, W2l, bufH, 256, W2r, b2l, bufS, N, 256);
    }
    // h2 = relu(LN(u2)) + h  (bufU dead -> reuse for h2)
    ln_relu_add<<<aggBlocks, 256, 0, stream>>>(bufS, bufH, g2, be2, bufU, N);

    // ---- layer 3 ----
    // out = agg(h2)@W3l + b3l + h2@W3r  == agg(h2@W3l) + (h2@W3r + b3l)
    // t3 = h2@W3l [N,128] (bufA128 reuse)
    {
        dim3 g((N + BM - 1) / BM, 128 / BN);
        gemm_dual<<<g, 256, 0, stream>>>(bufU, 256, W3l, nullptr, 0, nullptr, nullptr, bufA128, N, 128);
    }
    // r3 = h2@W3r + b3l [N,128]
    {
        dim3 g((N + BM - 1) / BM, 128 / BN);
        gemm_dual<<<g, 256, 0, stream>>>(bufU, 256, W3r, nullptr, 0, nullptr, b3l, bufB128, N, 128);
    }
    // out = mean-agg(t3) + r3
    agg_mean_128<<<aggBlocks, 256, 0, stream>>>(rowptr, col, invdeg, bufA128, bufB128,
                                                (float*)d_out, N);
}

// Round 2
// 696.836 us; speedup vs baseline: 1.4698x; 1.4698x over previous
//
#include <hip/hip_runtime.h>

// ---------------- problem dims (fixed by reference) ----------------
// N=50000, E=640000, DIN=128, DH=256, DOUT=128

typedef float floatx4 __attribute__((ext_vector_type(4)));
typedef short bf16x8 __attribute__((ext_vector_type(8)));

__device__ inline unsigned short f2bf(float f) {
    unsigned u = __float_as_uint(f);
    unsigned r = (u + 0x7fffu + ((u >> 16) & 1u)) >> 16;  // RNE
    return (unsigned short)r;
}
__device__ inline float bf2f_lo(unsigned v) { return __uint_as_float(v << 16); }
__device__ inline float bf2f_hi(unsigned v) { return __uint_as_float(v & 0xffff0000u); }

// async global->LDS, 16B per lane. LDS dest is wave-uniform base + lane*16;
// our per-thread lds addresses are exactly lane-contiguous per wave.
__device__ inline void gl_lds16(const void* g, void* l) {
    __builtin_amdgcn_global_load_lds((const __attribute__((address_space(1))) unsigned int*)g,
                                     (__attribute__((address_space(3))) unsigned int*)l,
                                     16, 0, 0);
}

// ================= CSR build =================
__global__ void hist_kernel(const int* __restrict__ dst, int* __restrict__ cnt, int E) {
    int i = blockIdx.x * blockDim.x + threadIdx.x;
    if (i < E) atomicAdd(&cnt[dst[i]], 1);
}

__global__ __launch_bounds__(1024) void scan_kernel(const int* __restrict__ cnt,
                                                    int* __restrict__ rowptr,
                                                    int* __restrict__ cursor,
                                                    float* __restrict__ invdeg, int N) {
    __shared__ int part[1024];
    int t = threadIdx.x;
    int chunk = (N + 1023) >> 10;
    int s = t * chunk;
    int e = s + chunk; if (e > N) e = N;
    int sum = 0;
    for (int i = s; i < e; i++) sum += cnt[i];
    part[t] = sum;
    __syncthreads();
    for (int off = 1; off < 1024; off <<= 1) {
        int v = 0;
        if (t >= off) v = part[t - off];
        __syncthreads();
        part[t] += v;
        __syncthreads();
    }
    int run = part[t] - sum;
    for (int i = s; i < e; i++) {
        rowptr[i] = run;
        cursor[i] = run;
        int c = cnt[i];
        invdeg[i] = 1.0f / (float)(c > 1 ? c : 1);
        run += c;
    }
    if (t == 1023) rowptr[N] = part[1023];
}

__global__ void scatter_kernel(const int* __restrict__ src, const int* __restrict__ dst,
                               int* __restrict__ cursor, int* __restrict__ col, int E) {
    int i = blockIdx.x * blockDim.x + threadIdx.x;
    if (i < E) {
        int p = atomicAdd(&cursor[dst[i]], 1);
        col[p] = src[i];
    }
}

// ================= weight prep: transpose fp32 [K,Nc] -> bf16 [Nc, ostride] =================
__global__ void transpose_w_bf16(const float* __restrict__ in, unsigned short* __restrict__ out,
                                 int K, int Nc, int ostride, int ooff) {
    int i = blockIdx.x * blockDim.x + threadIdx.x;
    if (i >= K * Nc) return;
    int k = i / Nc, n = i - k * Nc;
    out[(size_t)n * ostride + ooff + k] = f2bf(in[i]);
}

// x fp32 [N,128] -> bf16 into A1cat right half (stride 256)
__global__ void cvt_x_kernel(const float* __restrict__ x, unsigned short* __restrict__ A1cat, int total) {
    int i = blockIdx.x * blockDim.x + threadIdx.x;
    if (i >= total) return;
    int r = i >> 7, c = i & 127;
    A1cat[(size_t)r * 256 + 128 + c] = f2bf(x[i]);
}

// ================= CSR mean aggregation (bf16 in, bf16 out) =================
// one wave per destination node; 128 cols, lane handles 2 (4B load)
__global__ __launch_bounds__(256) void agg_bf16_128(const int* __restrict__ rowptr,
                                                    const int* __restrict__ col,
                                                    const float* __restrict__ invdeg,
                                                    const unsigned short* __restrict__ X, int xstride,
                                                    unsigned short* __restrict__ out, int ostride, int N) {
    int wid = (blockIdx.x * blockDim.x + threadIdx.x) >> 6;
    int lane = threadIdx.x & 63;
    if (wid >= N) return;
    int s = rowptr[wid], e = rowptr[wid + 1];
    float ax = 0.f, ay = 0.f;
    for (int j = s; j < e; j++) {
        int c = col[j];
        unsigned v = *(const unsigned*)(X + (size_t)c * xstride + lane * 2);
        ax += bf2f_lo(v);
        ay += bf2f_hi(v);
    }
    float inv = invdeg[wid];
    ushort2 o;
    o.x = f2bf(ax * inv);
    o.y = f2bf(ay * inv);
    *(ushort2*)(out + (size_t)wid * ostride + lane * 2) = o;
}

// 256 cols, lane handles 4 (8B load)
__global__ __launch_bounds__(256) void agg_bf16_256(const int* __restrict__ rowptr,
                                                    const int* __restrict__ col,
                                                    const float* __restrict__ invdeg,
                                                    const unsigned short* __restrict__ X, int xstride,
                                                    unsigned short* __restrict__ out, int ostride, int N) {
    int wid = (blockIdx.x * blockDim.x + threadIdx.x) >> 6;
    int lane = threadIdx.x & 63;
    if (wid >= N) return;
    int s = rowptr[wid], e = rowptr[wid + 1];
    float a0 = 0.f, a1 = 0.f, a2 = 0.f, a3 = 0.f;
    for (int j = s; j < e; j++) {
        int c = col[j];
        uint2 v = *(const uint2*)(X + (size_t)c * xstride + lane * 4);
        a0 += bf2f_lo(v.x); a1 += bf2f_hi(v.x);
        a2 += bf2f_lo(v.y); a3 += bf2f_hi(v.y);
    }
    float inv = invdeg[wid];
    ushort4 o;
    o.x = f2bf(a0 * inv); o.y = f2bf(a1 * inv);
    o.z = f2bf(a2 * inv); o.w = f2bf(a3 * inv);
    *(ushort4*)(out + (size_t)wid * ostride + lane * 4) = o;
}

// final: out = mean-agg(T bf16 [N,128]) + R fp32 [N,128], fp32 out
__global__ __launch_bounds__(256) void agg_final_128(const int* __restrict__ rowptr,
                                                     const int* __restrict__ col,
                                                     const float* __restrict__ invdeg,
                                                     const unsigned short* __restrict__ T,
                                                     const float* __restrict__ R,
                                                     float* __restrict__ out, int N) {
    int wid = (blockIdx.x * blockDim.x + threadIdx.x) >> 6;
    int lane = threadIdx.x & 63;
    if (wid >= N) return;
    int s = rowptr[wid], e = rowptr[wid + 1];
    float ax = 0.f, ay = 0.f;
    for (int j = s; j < e; j++) {
        int c = col[j];
        unsigned v = *(const unsigned*)(T + (size_t)c * 128 + lane * 2);
        ax += bf2f_lo(v);
        ay += bf2f_hi(v);
    }
    float inv = invdeg[wid];
    float2 r = *(const float2*)(R + (size_t)wid * 128 + lane * 2);
    float2 o;
    o.x = ax * inv + r.x;
    o.y = ay * inv + r.y;
    *(float2*)(out + (size_t)wid * 128 + lane * 2) = o;
}

// ================= bf16 MFMA GEMM: C = A@B^T(+bias) =================
// A bf16 row-major [M,K] (lda), B = W^T bf16 row-major [Nc,K] (ldb).
// 128x128 tile, BK=64, 256 threads = 4 waves in 2x2, each wave 4x4 of 16x16x32 MFMA.
__device__ inline void store_out(float* p, float v) { *p = v; }
__device__ inline void store_out(unsigned short* p, float v) { *p = f2bf(v); }

template <typename OT>
__global__ __launch_bounds__(256) void gemm_mfma(const unsigned short* __restrict__ A, int lda, int K,
                                                 const unsigned short* __restrict__ B, int ldb,
                                                 const float* __restrict__ bias,
                                                 OT* __restrict__ C, int ldc, int M) {
    __shared__ unsigned short sA[128 * 64];  // [row][k] row-major
    __shared__ unsigned short sB[128 * 64];  // [n][k]   row-major (B is W^T)
    int t = threadIdx.x;
    int bm = blockIdx.x * 128;
    int bn = blockIdx.y * 128;
    int lane = t & 63;
    int w = t >> 6;
    int wm = (w >> 1) * 64, wn = (w & 1) * 64;

    floatx4 acc[4][4];
#pragma unroll
    for (int i = 0; i < 4; i++)
#pragma unroll
        for (int j = 0; j < 4; j++) acc[i][j] = (floatx4){0.f, 0.f, 0.f, 0.f};

    // staging: chunk c = i*256 + t -> row = c>>3 = i*32 + (t>>3), kchunk = t&7
    const int rA0 = t >> 3;
    const int kc8 = (t & 7) * 8;

    for (int k0 = 0; k0 < K; k0 += 64) {
#pragma unroll
        for (int i = 0; i < 4; i++) {
            int row = bm + rA0 + i * 32;
            if (row > M - 1) row = M - 1;  // clamp (read valid garbage; output masked)
            gl_lds16(A + (size_t)row * lda + k0 + kc8, (void*)&sA[(size_t)(i * 256 + t) * 8]);
            gl_lds16(B + (size_t)(bn + rA0 + i * 32) * ldb + k0 + kc8,
                     (void*)&sB[(size_t)(i * 256 + t) * 8]);
        }
        __syncthreads();  // drains vmcnt before barrier
#pragma unroll
        for (int ks = 0; ks < 2; ks++) {
            bf16x8 af[4], bfr[4];
#pragma unroll
            for (int mi = 0; mi < 4; mi++)
                af[mi] = *(const bf16x8*)&sA[(wm + mi * 16 + (lane & 15)) * 64 + ks * 32 + (lane >> 4) * 8];
#pragma unroll
            for (int ni = 0; ni < 4; ni++)
                bfr[ni] = *(const bf16x8*)&sB[(wn + ni * 16 + (lane & 15)) * 64 + ks * 32 + (lane >> 4) * 8];
#pragma unroll
            for (int mi = 0; mi < 4; mi++)
#pragma unroll
                for (int ni = 0; ni < 4; ni++)
                    acc[mi][ni] = __builtin_amdgcn_mfma_f32_16x16x32_bf16(af[mi], bfr[ni], acc[mi][ni], 0, 0, 0);
        }
        __syncthreads();
    }

    // epilogue: C/D layout col=lane&15, row=(lane>>4)*4+reg
    int col0 = bn + wn + (lane & 15);
    int rbase = bm + wm + (lane >> 4) * 4;
#pragma unroll
    for (int ni = 0; ni < 4; ni++) {
        int col = col0 + ni * 16;
        float bv = bias ? bias[col] : 0.f;
#pragma unroll
        for (int mi = 0; mi < 4; mi++) {
#pragma unroll
            for (int r = 0; r < 4; r++) {
                int row = rbase + mi * 16 + r;
                if (row < M) store_out(C + (size_t)row * ldc + col, acc[mi][ni][r] + bv);
            }
        }
    }
}

// ================= LayerNorm(256) + ReLU + add, bf16 out =================
__global__ __launch_bounds__(256) void ln_fuse(const float* __restrict__ u,
                                               const float* __restrict__ addf,       // fp32 addend or null
                                               const unsigned short* __restrict__ addb, int abstride,
                                               const float* __restrict__ g, const float* __restrict__ b,
                                               unsigned short* __restrict__ out, int ostride, int N) {
    int row = (blockIdx.x * blockDim.x + threadIdx.x) >> 6;
    int lane = threadIdx.x & 63;
    if (row >= N) return;
    float4 v = *(const float4*)(u + (size_t)row * 256 + lane * 4);
    float s = v.x + v.y + v.z + v.w;
    float sq = v.x * v.x + v.y * v.y + v.z * v.z + v.w * v.w;
    for (int off = 1; off < 64; off <<= 1) {
        s += __shfl_xor(s, off, 64);
        sq += __shfl_xor(sq, off, 64);
    }
    float mu = s * (1.f / 256.f);
    float var = sq * (1.f / 256.f) - mu * mu;
    float rs = rsqrtf(var + 1e-5f);
    float4 gv = *(const float4*)(g + lane * 4);
    float4 bv = *(const float4*)(b + lane * 4);
    float a0, a1, a2, a3;
    if (addf) {
        float4 av = *(const float4*)(addf + (size_t)row * 256 + lane * 4);
        a0 = av.x; a1 = av.y; a2 = av.z; a3 = av.w;
    } else {
        uint2 av = *(const uint2*)(addb + (size_t)row * abstride + lane * 4);
        a0 = bf2f_lo(av.x); a1 = bf2f_hi(av.x);
        a2 = bf2f_lo(av.y); a3 = bf2f_hi(av.y);
    }
    ushort4 o;
    o.x = f2bf(fmaxf((v.x - mu) * rs * gv.x + bv.x, 0.f) + a0);
    o.y = f2bf(fmaxf((v.y - mu) * rs * gv.y + bv.y, 0.f) + a1);
    o.z = f2bf(fmaxf((v.z - mu) * rs * gv.z + bv.z, 0.f) + a2);
    o.w = f2bf(fmaxf((v.w - mu) * rs * gv.w + bv.w, 0.f) + a3);
    *(ushort4*)(out + (size_t)row * ostride + lane * 4) = o;
}

// ================= launch =================
extern "C" void kernel_launch(void* const* d_in, const int* in_sizes, int n_in,
                              void* d_out, int out_size, void* d_ws, size_t ws_size,
                              hipStream_t stream) {
    const float* x   = (const float*)d_in[0];
    const int*   ei  = (const int*)d_in[1];
    const float* W1l = (const float*)d_in[2];
    const float* b1l = (const float*)d_in[3];
    const float* W1r = (const float*)d_in[4];
    const float* g1  = (const float*)d_in[5];
    const float* be1 = (const float*)d_in[6];
    const float* Wsk = (const float*)d_in[7];
    const float* bsk = (const float*)d_in[8];
    const float* W2l = (const float*)d_in[9];
    const float* b2l = (const float*)d_in[10];
    const float* W2r = (const float*)d_in[11];
    const float* g2  = (const float*)d_in[12];
    const float* be2 = (const float*)d_in[13];
    const float* W3l = (const float*)d_in[14];
    const float* b3l = (const float*)d_in[15];
    const float* W3r = (const float*)d_in[16];

    const int N = in_sizes[0] / 128;
    const int E = in_sizes[1] / 2;
    const int* src = ei;
    const int* dst = ei + E;

    char* p = (char*)d_ws;
    auto alloc = [&](size_t bytes) {
        void* r = (void*)p;
        p += (bytes + 255) & ~(size_t)255;
        return r;
    };
    int*   cnt    = (int*)alloc(sizeof(int) * N);
    int*   rowptr = (int*)alloc(sizeof(int) * (N + 1));
    int*   cursor = (int*)alloc(sizeof(int) * N);
    float* invdeg = (float*)alloc(sizeof(float) * N);
    int*   col    = (int*)alloc(sizeof(int) * E);
    unsigned short* A1cat = (unsigned short*)alloc(sizeof(short) * (size_t)N * 256);  // [agg1|x] bf16; later t3
    unsigned short* A2cat = (unsigned short*)alloc(sizeof(short) * (size_t)N * 512);  // [agg2|h] bf16; later [h2|h]
    float* u    = (float*)alloc(sizeof(float) * (size_t)N * 256);   // u1, u2
    float* sbuf = (float*)alloc(sizeof(float) * (size_t)N * 256);   // s; later r3
    unsigned short* Wt1  = (unsigned short*)alloc(sizeof(short) * 256 * 256);
    unsigned short* Wts  = (unsigned short*)alloc(sizeof(short) * 256 * 128);
    unsigned short* Wt2  = (unsigned short*)alloc(sizeof(short) * 256 * 512);
    unsigned short* Wt3l = (unsigned short*)alloc(sizeof(short) * 128 * 256);
    unsigned short* Wt3r = (unsigned short*)alloc(sizeof(short) * 128 * 256);
    unsigned short* t3 = A1cat;            // [N,128] bf16 (A1cat dead by then)
    float*          r3 = sbuf;             // [N,128] fp32 (sbuf dead by then)

    // ---- CSR build ----
    hipMemsetAsync(cnt, 0, sizeof(int) * N, stream);
    hist_kernel<<<(E + 255) / 256, 256, 0, stream>>>(dst, cnt, E);
    scan_kernel<<<1, 1024, 0, stream>>>(cnt, rowptr, cursor, invdeg, N);
    scatter_kernel<<<(E + 255) / 256, 256, 0, stream>>>(src, dst, cursor, col, E);

    // ---- weight prep (bf16 transposed, K-concat where fused) ----
    transpose_w_bf16<<<(128 * 256 + 255) / 256, 256, 0, stream>>>(W1l, Wt1, 128, 256, 256, 0);
    transpose_w_bf16<<<(128 * 256 + 255) / 256, 256, 0, stream>>>(W1r, Wt1, 128, 256, 256, 128);
    transpose_w_bf16<<<(128 * 256 + 255) / 256, 256, 0, stream>>>(Wsk, Wts, 128, 256, 128, 0);
    transpose_w_bf16<<<(256 * 256 + 255) / 256, 256, 0, stream>>>(W2l, Wt2, 256, 256, 512, 0);
    transpose_w_bf16<<<(256 * 256 + 255) / 256, 256, 0, stream>>>(W2r, Wt2, 256, 256, 512, 256);
    transpose_w_bf16<<<(256 * 128 + 255) / 256, 256, 0, stream>>>(W3l, Wt3l, 256, 128, 256, 0);
    transpose_w_bf16<<<(256 * 128 + 255) / 256, 256, 0, stream>>>(W3r, Wt3r, 256, 128, 256, 0);
    cvt_x_kernel<<<((N * 128) + 255) / 256, 256, 0, stream>>>(x, A1cat, N * 128);

    int aggBlocks = (N + 3) / 4;
    int mBlocks = (N + 127) / 128;

    // ---- layer 1 ----
    agg_bf16_128<<<aggBlocks, 256, 0, stream>>>(rowptr, col, invdeg, A1cat + 128, 256, A1cat, 256, N);
    gemm_mfma<float><<<dim3(mBlocks, 2), 256, 0, stream>>>(A1cat, 256, 256, Wt1, 256, b1l, u, 256, N);
    gemm_mfma<float><<<dim3(mBlocks, 2), 256, 0, stream>>>(A1cat + 128, 256, 128, Wts, 128, bsk, sbuf, 256, N);
    // h = relu(LN(u1)) + s -> bf16 into A2cat right half
    ln_fuse<<<aggBlocks, 256, 0, stream>>>(u, sbuf, nullptr, 0, g1, be1, A2cat + 256, 512, N);

    // ---- layer 2 ----
    agg_bf16_256<<<aggBlocks, 256, 0, stream>>>(rowptr, col, invdeg, A2cat + 256, 512, A2cat, 512, N);
    gemm_mfma<float><<<dim3(mBlocks, 2), 256, 0, stream>>>(A2cat, 512, 512, Wt2, 512, b2l, u, 256, N);
    // h2 = relu(LN(u2)) + h -> bf16 into A2cat left half (agg2 dead)
    ln_fuse<<<aggBlocks, 256, 0, stream>>>(u, nullptr, A2cat + 256, 512, g2, be2, A2cat, 512, N);

    // ---- layer 3: out = agg(h2@W3l) + (h2@W3r + b3l) ----
    gemm_mfma<unsigned short><<<dim3(mBlocks, 1), 256, 0, stream>>>(A2cat, 512, 256, Wt3l, 256, nullptr, t3, 128, N);
    gemm_mfma<float><<<dim3(mBlocks, 1), 256, 0, stream>>>(A2cat, 512, 256, Wt3r, 256, b3l, r3, 128, N);
    agg_final_128<<<aggBlocks, 256, 0, stream>>>(rowptr, col, invdeg, t3, r3, (float*)d_out, N);
}

// Round 3
// 565.957 us; speedup vs baseline: 1.8097x; 1.2313x over previous
//
#include <hip/hip_runtime.h>

// ---------------- problem dims (fixed by reference) ----------------
// N=50000, E=640000, DIN=128, DH=256, DOUT=128

typedef float floatx4 __attribute__((ext_vector_type(4)));
typedef short bf16x8 __attribute__((ext_vector_type(8)));

__device__ inline unsigned short f2bf(float f) {
    unsigned u = __float_as_uint(f);
    unsigned r = (u + 0x7fffu + ((u >> 16) & 1u)) >> 16;  // RNE
    return (unsigned short)r;
}
__device__ inline float bf2f_lo(unsigned v) { return __uint_as_float(v << 16); }
__device__ inline float bf2f_hi(unsigned v) { return __uint_as_float(v & 0xffff0000u); }

__device__ inline void gl_lds16(const void* g, void* l) {
    __builtin_amdgcn_global_load_lds((const __attribute__((address_space(1))) unsigned int*)g,
                                     (__attribute__((address_space(3))) unsigned int*)l,
                                     16, 0, 0);
}

// ================= CSR build =================
__global__ void hist_kernel(const int* __restrict__ dst, int* __restrict__ cnt, int E) {
    int i = blockIdx.x * blockDim.x + threadIdx.x;
    if (i < E) atomicAdd(&cnt[dst[i]], 1);
}

// ---- multi-block scan: 2048 elements per 256-thread block ----
#define SCAN_CHUNK 2048

__global__ __launch_bounds__(256) void scan_blocksums(const int* __restrict__ cnt,
                                                      int* __restrict__ bsum, int N) {
    __shared__ int sh[256];
    int t = threadIdx.x;
    int base = blockIdx.x * SCAN_CHUNK + t * 8;
    int s = 0;
#pragma unroll
    for (int i = 0; i < 8; i++) {
        int idx = base + i;
        if (idx < N) s += cnt[idx];
    }
    sh[t] = s;
    __syncthreads();
    for (int off = 1; off < 256; off <<= 1) {
        int v = (t >= off) ? sh[t - off] : 0;
        __syncthreads();
        sh[t] += v;
        __syncthreads();
    }
    if (t == 255) bsum[blockIdx.x] = sh[255];
}

// single block scans the (<=256) block sums -> exclusive offsets; writes rowptr[N]=E
__global__ __launch_bounds__(256) void scan_bsums(const int* __restrict__ bsum,
                                                  int* __restrict__ boff, int NB,
                                                  int* __restrict__ rowptr, int N, int E) {
    __shared__ int sh[256];
    int t = threadIdx.x;
    int v = (t < NB) ? bsum[t] : 0;
    sh[t] = v;
    __syncthreads();
    for (int off = 1; off < 256; off <<= 1) {
        int u = (t >= off) ? sh[t - off] : 0;
        __syncthreads();
        sh[t] += u;
        __syncthreads();
    }
    if (t < NB) boff[t] = sh[t] - v;  // exclusive
    if (t == 0) rowptr[N] = E;
}

__global__ __launch_bounds__(256) void scan_final(const int* __restrict__ cnt,
                                                  const int* __restrict__ boff,
                                                  int* __restrict__ rowptr,
                                                  int* __restrict__ cursor,
                                                  float* __restrict__ invdeg, int N) {
    __shared__ int sh[256];
    int t = threadIdx.x;
    int base = blockIdx.x * SCAN_CHUNK + t * 8;
    int c[8];
    int s = 0;
#pragma unroll
    for (int i = 0; i < 8; i++) {
        int idx = base + i;
        c[i] = (idx < N) ? cnt[idx] : 0;
        s += c[i];
    }
    sh[t] = s;
    __syncthreads();
    for (int off = 1; off < 256; off <<= 1) {
        int v = (t >= off) ? sh[t - off] : 0;
        __syncthreads();
        sh[t] += v;
        __syncthreads();
    }
    int run = boff[blockIdx.x] + sh[t] - s;  // exclusive prefix for this thread
#pragma unroll
    for (int i = 0; i < 8; i++) {
        int idx = base + i;
        if (idx < N) {
            rowptr[idx] = run;
            cursor[idx] = run;
            invdeg[idx] = 1.0f / (float)(c[i] > 1 ? c[i] : 1);
            run += c[i];
        }
    }
}

__global__ void scatter_kernel(const int* __restrict__ src, const int* __restrict__ dst,
                               int* __restrict__ cursor, int* __restrict__ col, int E) {
    int i = blockIdx.x * blockDim.x + threadIdx.x;
    if (i < E) {
        int p = atomicAdd(&cursor[dst[i]], 1);
        col[p] = src[i];
    }
}

// ================= fused weight prep: all transposes fp32->bf16^T in one kernel =================
// segment sizes: W1l 32768 | W1r 32768 | Wsk 32768 | W2l 65536 | W2r 65536 | W3l 32768 | W3r 32768
__global__ void prep_weights(const float* __restrict__ W1l, const float* __restrict__ W1r,
                             const float* __restrict__ Wsk, const float* __restrict__ W2l,
                             const float* __restrict__ W2r, const float* __restrict__ W3l,
                             const float* __restrict__ W3r,
                             unsigned short* __restrict__ Wt1, unsigned short* __restrict__ Wts,
                             unsigned short* __restrict__ Wt2, unsigned short* __restrict__ Wt3l,
                             unsigned short* __restrict__ Wt3r) {
    int i = blockIdx.x * blockDim.x + threadIdx.x;
    if (i < 32768) {                 // W1l [128,256] -> Wt1[n*256+k]
        int k = i >> 8, n = i & 255;
        Wt1[n * 256 + k] = f2bf(W1l[i]);
    } else if (i < 65536) {          // W1r -> Wt1[n*256+128+k]
        int j = i - 32768, k = j >> 8, n = j & 255;
        Wt1[n * 256 + 128 + k] = f2bf(W1r[j]);
    } else if (i < 98304) {          // Wsk [128,256] -> Wts[n*128+k]
        int j = i - 65536, k = j >> 8, n = j & 255;
        Wts[n * 128 + k] = f2bf(Wsk[j]);
    } else if (i < 163840) {         // W2l [256,256] -> Wt2[n*512+k]
        int j = i - 98304, k = j >> 8, n = j & 255;
        Wt2[n * 512 + k] = f2bf(W2l[j]);
    } else if (i < 229376) {         // W2r -> Wt2[n*512+256+k]
        int j = i - 163840, k = j >> 8, n = j & 255;
        Wt2[n * 512 + 256 + k] = f2bf(W2r[j]);
    } else if (i < 262144) {         // W3l [256,128] -> Wt3l[n*256+k]
        int j = i - 229376, k = j >> 7, n = j & 127;
        Wt3l[n * 256 + k] = f2bf(W3l[j]);
    } else if (i < 294912) {         // W3r [256,128] -> Wt3r[n*256+k]
        int j = i - 262144, k = j >> 7, n = j & 127;
        Wt3r[n * 256 + k] = f2bf(W3r[j]);
    }
}

// x fp32 [N,128] -> bf16 into A1cat right half (stride 256)
__global__ void cvt_x_kernel(const float* __restrict__ x, unsigned short* __restrict__ A1cat, int total) {
    int i = blockIdx.x * blockDim.x + threadIdx.x;
    if (i >= total) return;
    int r = i >> 7, c = i & 127;
    A1cat[(size_t)r * 256 + 128 + c] = f2bf(x[i]);
}

// ================= CSR mean aggregation (bf16 in, bf16 out) =================
__global__ __launch_bounds__(256) void agg_bf16_128(const int* __restrict__ rowptr,
                                                    const int* __restrict__ col,
                                                    const float* __restrict__ invdeg,
                                                    const unsigned short* __restrict__ X, int xstride,
                                                    unsigned short* __restrict__ out, int ostride, int N) {
    int wid = (blockIdx.x * blockDim.x + threadIdx.x) >> 6;
    int lane = threadIdx.x & 63;
    if (wid >= N) return;
    int s = rowptr[wid], e = rowptr[wid + 1];
    float ax = 0.f, ay = 0.f;
    for (int j = s; j < e; j++) {
        int c = col[j];
        unsigned v = *(const unsigned*)(X + (size_t)c * xstride + lane * 2);
        ax += bf2f_lo(v);
        ay += bf2f_hi(v);
    }
    float inv = invdeg[wid];
    ushort2 o;
    o.x = f2bf(ax * inv);
    o.y = f2bf(ay * inv);
    *(ushort2*)(out + (size_t)wid * ostride + lane * 2) = o;
}

__global__ __launch_bounds__(256) void agg_bf16_256(const int* __restrict__ rowptr,
                                                    const int* __restrict__ col,
                                                    const float* __restrict__ invdeg,
                                                    const unsigned short* __restrict__ X, int xstride,
                                                    unsigned short* __restrict__ out, int ostride, int N) {
    int wid = (blockIdx.x * blockDim.x + threadIdx.x) >> 6;
    int lane = threadIdx.x & 63;
    if (wid >= N) return;
    int s = rowptr[wid], e = rowptr[wid + 1];
    float a0 = 0.f, a1 = 0.f, a2 = 0.f, a3 = 0.f;
    for (int j = s; j < e; j++) {
        int c = col[j];
        uint2 v = *(const uint2*)(X + (size_t)c * xstride + lane * 4);
        a0 += bf2f_lo(v.x); a1 += bf2f_hi(v.x);
        a2 += bf2f_lo(v.y); a3 += bf2f_hi(v.y);
    }
    float inv = invdeg[wid];
    ushort4 o;
    o.x = f2bf(a0 * inv); o.y = f2bf(a1 * inv);
    o.z = f2bf(a2 * inv); o.w = f2bf(a3 * inv);
    *(ushort4*)(out + (size_t)wid * ostride + lane * 4) = o;
}

// final: out = mean-agg(T bf16 [N,128]) + R fp32 [N,128], fp32 out
__global__ __launch_bounds__(256) void agg_final_128(const int* __restrict__ rowptr,
                                                     const int* __restrict__ col,
                                                     const float* __restrict__ invdeg,
                                                     const unsigned short* __restrict__ T,
                                                     const float* __restrict__ R,
                                                     float* __restrict__ out, int N) {
    int wid = (blockIdx.x * blockDim.x + threadIdx.x) >> 6;
    int lane = threadIdx.x & 63;
    if (wid >= N) return;
    int s = rowptr[wid], e = rowptr[wid + 1];
    float ax = 0.f, ay = 0.f;
    for (int j = s; j < e; j++) {
        int c = col[j];
        unsigned v = *(const unsigned*)(T + (size_t)c * 128 + lane * 2);
        ax += bf2f_lo(v);
        ay += bf2f_hi(v);
    }
    float inv = invdeg[wid];
    float2 r = *(const float2*)(R + (size_t)wid * 128 + lane * 2);
    float2 o;
    o.x = ax * inv + r.x;
    o.y = ay * inv + r.y;
    *(float2*)(out + (size_t)wid * 128 + lane * 2) = o;
}

// ================= bf16 MFMA GEMM: C = A@B^T(+bias) =================
__device__ inline void store_out(float* p, float v) { *p = v; }
__device__ inline void store_out(unsigned short* p, float v) { *p = f2bf(v); }

template <typename OT>
__global__ __launch_bounds__(256) void gemm_mfma(const unsigned short* __restrict__ A, int lda, int K,
                                                 const unsigned short* __restrict__ B, int ldb,
                                                 const float* __restrict__ bias,
                                                 OT* __restrict__ C, int ldc, int M) {
    __shared__ unsigned short sA[128 * 64];  // [row][k]
    __shared__ unsigned short sB[128 * 64];  // [n][k]
    int t = threadIdx.x;
    int bm = blockIdx.x * 128;
    int bn = blockIdx.y * 128;
    int lane = t & 63;
    int w = t >> 6;
    int wm = (w >> 1) * 64, wn = (w & 1) * 64;

    floatx4 acc[4][4];
#pragma unroll
    for (int i = 0; i < 4; i++)
#pragma unroll
        for (int j = 0; j < 4; j++) acc[i][j] = (floatx4){0.f, 0.f, 0.f, 0.f};

    const int rA0 = t >> 3;
    const int kc8 = (t & 7) * 8;

    for (int k0 = 0; k0 < K; k0 += 64) {
#pragma unroll
        for (int i = 0; i < 4; i++) {
            int row = bm + rA0 + i * 32;
            if (row > M - 1) row = M - 1;  // clamp (output masked)
            gl_lds16(A + (size_t)row * lda + k0 + kc8, (void*)&sA[(size_t)(i * 256 + t) * 8]);
            gl_lds16(B + (size_t)(bn + rA0 + i * 32) * ldb + k0 + kc8,
                     (void*)&sB[(size_t)(i * 256 + t) * 8]);
        }
        __syncthreads();
#pragma unroll
        for (int ks = 0; ks < 2; ks++) {
            bf16x8 af[4], bfr[4];
#pragma unroll
            for (int mi = 0; mi < 4; mi++)
                af[mi] = *(const bf16x8*)&sA[(wm + mi * 16 + (lane & 15)) * 64 + ks * 32 + (lane >> 4) * 8];
#pragma unroll
            for (int ni = 0; ni < 4; ni++)
                bfr[ni] = *(const bf16x8*)&sB[(wn + ni * 16 + (lane & 15)) * 64 + ks * 32 + (lane >> 4) * 8];
#pragma unroll
            for (int mi = 0; mi < 4; mi++)
#pragma unroll
                for (int ni = 0; ni < 4; ni++)
                    acc[mi][ni] = __builtin_amdgcn_mfma_f32_16x16x32_bf16(af[mi], bfr[ni], acc[mi][ni], 0, 0, 0);
        }
        __syncthreads();
    }

    int col0 = bn + wn + (lane & 15);
    int rbase = bm + wm + (lane >> 4) * 4;
#pragma unroll
    for (int ni = 0; ni < 4; ni++) {
        int col = col0 + ni * 16;
        float bv = bias ? bias[col] : 0.f;
#pragma unroll
        for (int mi = 0; mi < 4; mi++) {
#pragma unroll
            for (int r = 0; r < 4; r++) {
                int row = rbase + mi * 16 + r;
                if (row < M) store_out(C + (size_t)row * ldc + col, acc[mi][ni][r] + bv);
            }
        }
    }
}

// ================= LayerNorm(256) + ReLU + add, bf16 out =================
__global__ __launch_bounds__(256) void ln_fuse(const float* __restrict__ u,
                                               const float* __restrict__ addf,
                                               const unsigned short* __restrict__ addb, int abstride,
                                               const float* __restrict__ g, const float* __restrict__ b,
                                               unsigned short* __restrict__ out, int ostride, int N) {
    int row = (blockIdx.x * blockDim.x + threadIdx.x) >> 6;
    int lane = threadIdx.x & 63;
    if (row >= N) return;
    float4 v = *(const float4*)(u + (size_t)row * 256 + lane * 4);
    float s = v.x + v.y + v.z + v.w;
    float sq = v.x * v.x + v.y * v.y + v.z * v.z + v.w * v.w;
    for (int off = 1; off < 64; off <<= 1) {
        s += __shfl_xor(s, off, 64);
        sq += __shfl_xor(sq, off, 64);
    }
    float mu = s * (1.f / 256.f);
    float var = sq * (1.f / 256.f) - mu * mu;
    float rs = rsqrtf(var + 1e-5f);
    float4 gv = *(const float4*)(g + lane * 4);
    float4 bv = *(const float4*)(b + lane * 4);
    float a0, a1, a2, a3;
    if (addf) {
        float4 av = *(const float4*)(addf + (size_t)row * 256 + lane * 4);
        a0 = av.x; a1 = av.y; a2 = av.z; a3 = av.w;
    } else {
        uint2 av = *(const uint2*)(addb + (size_t)row * abstride + lane * 4);
        a0 = bf2f_lo(av.x); a1 = bf2f_hi(av.x);
        a2 = bf2f_lo(av.y); a3 = bf2f_hi(av.y);
    }
    ushort4 o;
    o.x = f2bf(fmaxf((v.x - mu) * rs * gv.x + bv.x, 0.f) + a0);
    o.y = f2bf(fmaxf((v.y - mu) * rs * gv.y + bv.y, 0.f) + a1);
    o.z = f2bf(fmaxf((v.z - mu) * rs * gv.z + bv.z, 0.f) + a2);
    o.w = f2bf(fmaxf((v.w - mu) * rs * gv.w + bv.w, 0.f) + a3);
    *(ushort4*)(out + (size_t)row * ostride + lane * 4) = o;
}

// ================= launch =================
extern "C" void kernel_launch(void* const* d_in, const int* in_sizes, int n_in,
                              void* d_out, int out_size, void* d_ws, size_t ws_size,
                              hipStream_t stream) {
    const float* x   = (const float*)d_in[0];
    const int*   ei  = (const int*)d_in[1];
    const float* W1l = (const float*)d_in[2];
    const float* b1l = (const float*)d_in[3];
    const float* W1r = (const float*)d_in[4];
    const float* g1  = (const float*)d_in[5];
    const float* be1 = (const float*)d_in[6];
    const float* Wsk = (const float*)d_in[7];
    const float* bsk = (const float*)d_in[8];
    const float* W2l = (const float*)d_in[9];
    const float* b2l = (const float*)d_in[10];
    const float* W2r = (const float*)d_in[11];
    const float* g2  = (const float*)d_in[12];
    const float* be2 = (const float*)d_in[13];
    const float* W3l = (const float*)d_in[14];
    const float* b3l = (const float*)d_in[15];
    const float* W3r = (const float*)d_in[16];

    const int N = in_sizes[0] / 128;
    const int E = in_sizes[1] / 2;
    const int* src = ei;
    const int* dst = ei + E;

    char* p = (char*)d_ws;
    auto alloc = [&](size_t bytes) {
        void* r = (void*)p;
        p += (bytes + 255) & ~(size_t)255;
        return r;
    };
    int*   cnt    = (int*)alloc(sizeof(int) * N);
    int*   rowptr = (int*)alloc(sizeof(int) * (N + 1));
    int*   cursor = (int*)alloc(sizeof(int) * N);
    float* invdeg = (float*)alloc(sizeof(float) * N);
    int*   col    = (int*)alloc(sizeof(int) * E);
    int*   bsum   = (int*)alloc(sizeof(int) * 256);
    int*   boff   = (int*)alloc(sizeof(int) * 256);
    unsigned short* A1cat = (unsigned short*)alloc(sizeof(short) * (size_t)N * 256);  // [agg1|x]; later t3
    unsigned short* A2cat = (unsigned short*)alloc(sizeof(short) * (size_t)N * 512);  // [agg2|h]; later [h2|h]
    float* u    = (float*)alloc(sizeof(float) * (size_t)N * 256);   // u1, u2
    float* sbuf = (float*)alloc(sizeof(float) * (size_t)N * 256);   // s; later r3
    unsigned short* Wt1  = (unsigned short*)alloc(sizeof(short) * 256 * 256);
    unsigned short* Wts  = (unsigned short*)alloc(sizeof(short) * 256 * 128);
    unsigned short* Wt2  = (unsigned short*)alloc(sizeof(short) * 256 * 512);
    unsigned short* Wt3l = (unsigned short*)alloc(sizeof(short) * 128 * 256);
    unsigned short* Wt3r = (unsigned short*)alloc(sizeof(short) * 128 * 256);
    unsigned short* t3 = A1cat;
    float*          r3 = sbuf;

    // ---- CSR build ----
    hipMemsetAsync(cnt, 0, sizeof(int) * N, stream);
    hist_kernel<<<(E + 255) / 256, 256, 0, stream>>>(dst, cnt, E);
    int NB = (N + SCAN_CHUNK - 1) / SCAN_CHUNK;  // 25 for N=50000 (<=256 supported)
    scan_blocksums<<<NB, 256, 0, stream>>>(cnt, bsum, N);
    scan_bsums<<<1, 256, 0, stream>>>(bsum, boff, NB, rowptr, N, E);
    scan_final<<<NB, 256, 0, stream>>>(cnt, boff, rowptr, cursor, invdeg, N);
    scatter_kernel<<<(E + 255) / 256, 256, 0, stream>>>(src, dst, cursor, col, E);

    // ---- prep: fused weight transposes + x conversion ----
    prep_weights<<<(294912 + 255) / 256, 256, 0, stream>>>(W1l, W1r, Wsk, W2l, W2r, W3l, W3r,
                                                           Wt1, Wts, Wt2, Wt3l, Wt3r);
    cvt_x_kernel<<<((N * 128) + 255) / 256, 256, 0, stream>>>(x, A1cat, N * 128);

    int aggBlocks = (N + 3) / 4;
    int mBlocks = (N + 127) / 128;

    // ---- layer 1 ----
    agg_bf16_128<<<aggBlocks, 256, 0, stream>>>(rowptr, col, invdeg, A1cat + 128, 256, A1cat, 256, N);
    gemm_mfma<float><<<dim3(mBlocks, 2), 256, 0, stream>>>(A1cat, 256, 256, Wt1, 256, b1l, u, 256, N);
    gemm_mfma<float><<<dim3(mBlocks, 2), 256, 0, stream>>>(A1cat + 128, 256, 128, Wts, 128, bsk, sbuf, 256, N);
    ln_fuse<<<aggBlocks, 256, 0, stream>>>(u, sbuf, nullptr, 0, g1, be1, A2cat + 256, 512, N);

    // ---- layer 2 ----
    agg_bf16_256<<<aggBlocks, 256, 0, stream>>>(rowptr, col, invdeg, A2cat + 256, 512, A2cat, 512, N);
    gemm_mfma<float><<<dim3(mBlocks, 2), 256, 0, stream>>>(A2cat, 512, 512, Wt2, 512, b2l, u, 256, N);
    ln_fuse<<<aggBlocks, 256, 0, stream>>>(u, nullptr, A2cat + 256, 512, g2, be2, A2cat, 512, N);

    // ---- layer 3: out = agg(h2@W3l) + (h2@W3r + b3l) ----
    gemm_mfma<unsigned short><<<dim3(mBlocks, 1), 256, 0, stream>>>(A2cat, 512, 256, Wt3l, 256, nullptr, t3, 128, N);
    gemm_mfma<float><<<dim3(mBlocks, 1), 256, 0, stream>>>(A2cat, 512, 256, Wt3r, 256, b3l, r3, 128, N);
    agg_final_128<<<aggBlocks, 256, 0, stream>>>(rowptr, col, invdeg, t3, r3, (float*)d_out, N);
}

// Round 4
// 486.547 us; speedup vs baseline: 2.1050x; 1.1632x over previous
//
#include <hip/hip_runtime.h>

// ---------------- problem dims (fixed by reference) ----------------
// N=50000, E=640000, DIN=128, DH=256, DOUT=128

typedef float floatx4 __attribute__((ext_vector_type(4)));
typedef short bf16x8 __attribute__((ext_vector_type(8)));

__device__ inline unsigned short f2bf(float f) {
    unsigned u = __float_as_uint(f);
    unsigned r = (u + 0x7fffu + ((u >> 16) & 1u)) >> 16;  // RNE
    return (unsigned short)r;
}
__device__ inline float bf2f_lo(unsigned v) { return __uint_as_float(v << 16); }
__device__ inline float bf2f_hi(unsigned v) { return __uint_as_float(v & 0xffff0000u); }

__device__ inline void gl_lds16(const void* g, void* l) {
    __builtin_amdgcn_global_load_lds((const __attribute__((address_space(1))) unsigned int*)g,
                                     (__attribute__((address_space(3))) unsigned int*)l,
                                     16, 0, 0);
}

// ================= CSR build =================
__global__ void hist_kernel(const int* __restrict__ dst, int* __restrict__ cnt, int E) {
    int i = blockIdx.x * blockDim.x + threadIdx.x;
    if (i < E) atomicAdd(&cnt[dst[i]], 1);
}

#define SCAN_CHUNK 2048

__global__ __launch_bounds__(256) void scan_blocksums(const int* __restrict__ cnt,
                                                      int* __restrict__ bsum, int N) {
    __shared__ int sh[256];
    int t = threadIdx.x;
    int base = blockIdx.x * SCAN_CHUNK + t * 8;
    int s = 0;
#pragma unroll
    for (int i = 0; i < 8; i++) {
        int idx = base + i;
        if (idx < N) s += cnt[idx];
    }
    sh[t] = s;
    __syncthreads();
    for (int off = 1; off < 256; off <<= 1) {
        int v = (t >= off) ? sh[t - off] : 0;
        __syncthreads();
        sh[t] += v;
        __syncthreads();
    }
    if (t == 255) bsum[blockIdx.x] = sh[255];
}

__global__ __launch_bounds__(256) void scan_bsums(const int* __restrict__ bsum,
                                                  int* __restrict__ boff, int NB,
                                                  int* __restrict__ rowptr, int N, int E) {
    __shared__ int sh[256];
    int t = threadIdx.x;
    int v = (t < NB) ? bsum[t] : 0;
    sh[t] = v;
    __syncthreads();
    for (int off = 1; off < 256; off <<= 1) {
        int u = (t >= off) ? sh[t - off] : 0;
        __syncthreads();
        sh[t] += u;
        __syncthreads();
    }
    if (t < NB) boff[t] = sh[t] - v;
    if (t == 0) rowptr[N] = E;
}

__global__ __launch_bounds__(256) void scan_final(const int* __restrict__ cnt,
                                                  const int* __restrict__ boff,
                                                  int* __restrict__ rowptr,
                                                  int* __restrict__ cursor,
                                                  float* __restrict__ invdeg, int N) {
    __shared__ int sh[256];
    int t = threadIdx.x;
    int base = blockIdx.x * SCAN_CHUNK + t * 8;
    int c[8];
    int s = 0;
#pragma unroll
    for (int i = 0; i < 8; i++) {
        int idx = base + i;
        c[i] = (idx < N) ? cnt[idx] : 0;
        s += c[i];
    }
    sh[t] = s;
    __syncthreads();
    for (int off = 1; off < 256; off <<= 1) {
        int v = (t >= off) ? sh[t - off] : 0;
        __syncthreads();
        sh[t] += v;
        __syncthreads();
    }
    int run = boff[blockIdx.x] + sh[t] - s;
#pragma unroll
    for (int i = 0; i < 8; i++) {
        int idx = base + i;
        if (idx < N) {
            rowptr[idx] = run;
            cursor[idx] = run;
            invdeg[idx] = 1.0f / (float)(c[i] > 1 ? c[i] : 1);
            run += c[i];
        }
    }
}

__global__ void scatter_kernel(const int* __restrict__ src, const int* __restrict__ dst,
                               int* __restrict__ cursor, int* __restrict__ col, int E) {
    int i = blockIdx.x * blockDim.x + threadIdx.x;
    if (i < E) {
        int p = atomicAdd(&cursor[dst[i]], 1);
        col[p] = src[i];
    }
}

// ================= fused weight prep =================
// W1l 32768 | W1r 32768 | Wsk 32768 | W2l 65536 | W2r 65536 | W3l 32768 | W3r 32768
// Wt3 combined [256,256]: rows 0-127 = W3l^T, rows 128-255 = W3r^T
__global__ void prep_weights(const float* __restrict__ W1l, const float* __restrict__ W1r,
                             const float* __restrict__ Wsk, const float* __restrict__ W2l,
                             const float* __restrict__ W2r, const float* __restrict__ W3l,
                             const float* __restrict__ W3r,
                             unsigned short* __restrict__ Wt1, unsigned short* __restrict__ Wts,
                             unsigned short* __restrict__ Wt2, unsigned short* __restrict__ Wt3) {
    int i = blockIdx.x * blockDim.x + threadIdx.x;
    if (i < 32768) {
        int k = i >> 8, n = i & 255;
        Wt1[n * 256 + k] = f2bf(W1l[i]);
    } else if (i < 65536) {
        int j = i - 32768, k = j >> 8, n = j & 255;
        Wt1[n * 256 + 128 + k] = f2bf(W1r[j]);
    } else if (i < 98304) {
        int j = i - 65536, k = j >> 8, n = j & 255;
        Wts[n * 128 + k] = f2bf(Wsk[j]);
    } else if (i < 163840) {
        int j = i - 98304, k = j >> 8, n = j & 255;
        Wt2[n * 512 + k] = f2bf(W2l[j]);
    } else if (i < 229376) {
        int j = i - 163840, k = j >> 8, n = j & 255;
        Wt2[n * 512 + 256 + k] = f2bf(W2r[j]);
    } else if (i < 262144) {
        int j = i - 229376, k = j >> 7, n = j & 127;
        Wt3[n * 256 + k] = f2bf(W3l[j]);
    } else if (i < 294912) {
        int j = i - 262144, k = j >> 7, n = j & 127;
        Wt3[(128 + n) * 256 + k] = f2bf(W3r[j]);
    }
}

__global__ void cvt_x_kernel(const float* __restrict__ x, unsigned short* __restrict__ A1cat, int total) {
    int i = blockIdx.x * blockDim.x + threadIdx.x;
    if (i >= total) return;
    int r = i >> 7, c = i & 127;
    A1cat[(size_t)r * 256 + 128 + c] = f2bf(x[i]);
}

// ================= CSR mean aggregation (bf16 in, bf16 out) =================
// one wave per (node, 128-col slice); edge loop unrolled x4 for MLP.
// grid.y = number of 128-col slices.
__global__ __launch_bounds__(256) void agg_bf16(const int* __restrict__ rowptr,
                                                const int* __restrict__ col,
                                                const float* __restrict__ invdeg,
                                                const unsigned short* __restrict__ X, int xstride,
                                                unsigned short* __restrict__ out, int ostride, int N) {
    int wid = (blockIdx.x * blockDim.x + threadIdx.x) >> 6;
    int lane = threadIdx.x & 63;
    if (wid >= N) return;
    int off = blockIdx.y * 128 + lane * 2;
    const unsigned short* Xo = X + off;
    int s = rowptr[wid], e = rowptr[wid + 1];
    float ax = 0.f, ay = 0.f;
    int j = s;
    for (; j + 4 <= e; j += 4) {
        int c0 = col[j], c1 = col[j + 1], c2 = col[j + 2], c3 = col[j + 3];
        unsigned v0 = *(const unsigned*)(Xo + (size_t)c0 * xstride);
        unsigned v1 = *(const unsigned*)(Xo + (size_t)c1 * xstride);
        unsigned v2 = *(const unsigned*)(Xo + (size_t)c2 * xstride);
        unsigned v3 = *(const unsigned*)(Xo + (size_t)c3 * xstride);
        ax += (bf2f_lo(v0) + bf2f_lo(v1)) + (bf2f_lo(v2) + bf2f_lo(v3));
        ay += (bf2f_hi(v0) + bf2f_hi(v1)) + (bf2f_hi(v2) + bf2f_hi(v3));
    }
    for (; j < e; j++) {
        unsigned v = *(const unsigned*)(Xo + (size_t)col[j] * xstride);
        ax += bf2f_lo(v);
        ay += bf2f_hi(v);
    }
    float inv = invdeg[wid];
    ushort2 o;
    o.x = f2bf(ax * inv);
    o.y = f2bf(ay * inv);
    *(ushort2*)(out + (size_t)wid * ostride + off) = o;
}

// final: out = mean-agg(T bf16 [N,128]) + R fp32 [N,128], fp32 out; unrolled x4
__global__ __launch_bounds__(256) void agg_final_128(const int* __restrict__ rowptr,
                                                     const int* __restrict__ col,
                                                     const float* __restrict__ invdeg,
                                                     const unsigned short* __restrict__ T,
                                                     const float* __restrict__ R,
                                                     float* __restrict__ out, int N) {
    int wid = (blockIdx.x * blockDim.x + threadIdx.x) >> 6;
    int lane = threadIdx.x & 63;
    if (wid >= N) return;
    const unsigned short* To = T + lane * 2;
    int s = rowptr[wid], e = rowptr[wid + 1];
    float ax = 0.f, ay = 0.f;
    int j = s;
    for (; j + 4 <= e; j += 4) {
        int c0 = col[j], c1 = col[j + 1], c2 = col[j + 2], c3 = col[j + 3];
        unsigned v0 = *(const unsigned*)(To + (size_t)c0 * 128);
        unsigned v1 = *(const unsigned*)(To + (size_t)c1 * 128);
        unsigned v2 = *(const unsigned*)(To + (size_t)c2 * 128);
        unsigned v3 = *(const unsigned*)(To + (size_t)c3 * 128);
        ax += (bf2f_lo(v0) + bf2f_lo(v1)) + (bf2f_lo(v2) + bf2f_lo(v3));
        ay += (bf2f_hi(v0) + bf2f_hi(v1)) + (bf2f_hi(v2) + bf2f_hi(v3));
    }
    for (; j < e; j++) {
        unsigned v = *(const unsigned*)(To + (size_t)col[j] * 128);
        ax += bf2f_lo(v);
        ay += bf2f_hi(v);
    }
    float inv = invdeg[wid];
    float2 r = *(const float2*)(R + (size_t)wid * 128 + lane * 2);
    float2 o;
    o.x = ax * inv + r.x;
    o.y = ay * inv + r.y;
    *(float2*)(out + (size_t)wid * 128 + lane * 2) = o;
}

// ================= bf16 MFMA GEMM: C = A@B^T(+bias) =================
__device__ inline void store_out(float* p, float v) { *p = v; }
__device__ inline void store_out(unsigned short* p, float v) { *p = f2bf(v); }

template <typename OT>
__global__ __launch_bounds__(256) void gemm_mfma(const unsigned short* __restrict__ A, int lda, int K,
                                                 const unsigned short* __restrict__ B, int ldb,
                                                 const float* __restrict__ bias,
                                                 OT* __restrict__ C, int ldc, int M) {
    __shared__ unsigned short sA[128 * 64];  // [row][k]
    __shared__ unsigned short sB[128 * 64];  // [n][k]
    int t = threadIdx.x;
    int bm = blockIdx.x * 128;
    int bn = blockIdx.y * 128;
    int lane = t & 63;
    int w = t >> 6;
    int wm = (w >> 1) * 64, wn = (w & 1) * 64;

    floatx4 acc[4][4];
#pragma unroll
    for (int i = 0; i < 4; i++)
#pragma unroll
        for (int j = 0; j < 4; j++) acc[i][j] = (floatx4){0.f, 0.f, 0.f, 0.f};

    const int rA0 = t >> 3;
    const int kc8 = (t & 7) * 8;

    for (int k0 = 0; k0 < K; k0 += 64) {
#pragma unroll
        for (int i = 0; i < 4; i++) {
            int row = bm + rA0 + i * 32;
            if (row > M - 1) row = M - 1;
            gl_lds16(A + (size_t)row * lda + k0 + kc8, (void*)&sA[(size_t)(i * 256 + t) * 8]);
            gl_lds16(B + (size_t)(bn + rA0 + i * 32) * ldb + k0 + kc8,
                     (void*)&sB[(size_t)(i * 256 + t) * 8]);
        }
        __syncthreads();
#pragma unroll
        for (int ks = 0; ks < 2; ks++) {
            bf16x8 af[4], bfr[4];
#pragma unroll
            for (int mi = 0; mi < 4; mi++)
                af[mi] = *(const bf16x8*)&sA[(wm + mi * 16 + (lane & 15)) * 64 + ks * 32 + (lane >> 4) * 8];
#pragma unroll
            for (int ni = 0; ni < 4; ni++)
                bfr[ni] = *(const bf16x8*)&sB[(wn + ni * 16 + (lane & 15)) * 64 + ks * 32 + (lane >> 4) * 8];
#pragma unroll
            for (int mi = 0; mi < 4; mi++)
#pragma unroll
                for (int ni = 0; ni < 4; ni++)
                    acc[mi][ni] = __builtin_amdgcn_mfma_f32_16x16x32_bf16(af[mi], bfr[ni], acc[mi][ni], 0, 0, 0);
        }
        __syncthreads();
    }

    int col0 = bn + wn + (lane & 15);
    int rbase = bm + wm + (lane >> 4) * 4;
#pragma unroll
    for (int ni = 0; ni < 4; ni++) {
        int col = col0 + ni * 16;
        float bv = bias ? bias[col] : 0.f;
#pragma unroll
        for (int mi = 0; mi < 4; mi++) {
#pragma unroll
            for (int r = 0; r < 4; r++) {
                int row = rbase + mi * 16 + r;
                if (row < M) store_out(C + (size_t)row * ldc + col, acc[mi][ni][r] + bv);
            }
        }
    }
}

// L3 split-epilogue GEMM: C[N,256] where cols 0-127 -> T bf16, cols 128-255 -> R fp32 + bias
__global__ __launch_bounds__(256) void gemm_mfma_l3(const unsigned short* __restrict__ A, int lda, int K,
                                                    const unsigned short* __restrict__ B, int ldb,
                                                    const float* __restrict__ bias,
                                                    unsigned short* __restrict__ T,
                                                    float* __restrict__ R, int M) {
    __shared__ unsigned short sA[128 * 64];
    __shared__ unsigned short sB[128 * 64];
    int t = threadIdx.x;
    int bm = blockIdx.x * 128;
    int bn = blockIdx.y * 128;
    int lane = t & 63;
    int w = t >> 6;
    int wm = (w >> 1) * 64, wn = (w & 1) * 64;

    floatx4 acc[4][4];
#pragma unroll
    for (int i = 0; i < 4; i++)
#pragma unroll
        for (int j = 0; j < 4; j++) acc[i][j] = (floatx4){0.f, 0.f, 0.f, 0.f};

    const int rA0 = t >> 3;
    const int kc8 = (t & 7) * 8;

    for (int k0 = 0; k0 < K; k0 += 64) {
#pragma unroll
        for (int i = 0; i < 4; i++) {
            int row = bm + rA0 + i * 32;
            if (row > M - 1) row = M - 1;
            gl_lds16(A + (size_t)row * lda + k0 + kc8, (void*)&sA[(size_t)(i * 256 + t) * 8]);
            gl_lds16(B + (size_t)(bn + rA0 + i * 32) * ldb + k0 + kc8,
                     (void*)&sB[(size_t)(i * 256 + t) * 8]);
        }
        __syncthreads();
#pragma unroll
        for (int ks = 0; ks < 2; ks++) {
            bf16x8 af[4], bfr[4];
#pragma unroll
            for (int mi = 0; mi < 4; mi++)
                af[mi] = *(const bf16x8*)&sA[(wm + mi * 16 + (lane & 15)) * 64 + ks * 32 + (lane >> 4) * 8];
#pragma unroll
            for (int ni = 0; ni < 4; ni++)
                bfr[ni] = *(const bf16x8*)&sB[(wn + ni * 16 + (lane & 15)) * 64 + ks * 32 + (lane >> 4) * 8];
#pragma unroll
            for (int mi = 0; mi < 4; mi++)
#pragma unroll
                for (int ni = 0; ni < 4; ni++)
                    acc[mi][ni] = __builtin_amdgcn_mfma_f32_16x16x32_bf16(af[mi], bfr[ni], acc[mi][ni], 0, 0, 0);
        }
        __syncthreads();
    }

    int col0 = bn + wn + (lane & 15);
    int rbase = bm + wm + (lane >> 4) * 4;
#pragma unroll
    for (int ni = 0; ni < 4; ni++) {
        int col = col0 + ni * 16;
        if (col < 128) {
#pragma unroll
            for (int mi = 0; mi < 4; mi++)
#pragma unroll
                for (int r = 0; r < 4; r++) {
                    int row = rbase + mi * 16 + r;
                    if (row < M) T[(size_t)row * 128 + col] = f2bf(acc[mi][ni][r]);
                }
        } else {
            float bv = bias[col - 128];
#pragma unroll
            for (int mi = 0; mi < 4; mi++)
#pragma unroll
                for (int r = 0; r < 4; r++) {
                    int row = rbase + mi * 16 + r;
                    if (row < M) R[(size_t)row * 128 + col - 128] = acc[mi][ni][r] + bv;
                }
        }
    }
}

// ================= LayerNorm(256) + ReLU + add, bf16 out =================
__global__ __launch_bounds__(256) void ln_fuse(const float* __restrict__ u,
                                               const float* __restrict__ addf,
                                               const unsigned short* __restrict__ addb, int abstride,
                                               const float* __restrict__ g, const float* __restrict__ b,
                                               unsigned short* __restrict__ out, int ostride, int N) {
    int row = (blockIdx.x * blockDim.x + threadIdx.x) >> 6;
    int lane = threadIdx.x & 63;
    if (row >= N) return;
    float4 v = *(const float4*)(u + (size_t)row * 256 + lane * 4);
    float s = v.x + v.y + v.z + v.w;
    float sq = v.x * v.x + v.y * v.y + v.z * v.z + v.w * v.w;
    for (int off = 1; off < 64; off <<= 1) {
        s += __shfl_xor(s, off, 64);
        sq += __shfl_xor(sq, off, 64);
    }
    float mu = s * (1.f / 256.f);
    float var = sq * (1.f / 256.f) - mu * mu;
    float rs = rsqrtf(var + 1e-5f);
    float4 gv = *(const float4*)(g + lane * 4);
    float4 bv = *(const float4*)(b + lane * 4);
    float a0, a1, a2, a3;
    if (addf) {
        float4 av = *(const float4*)(addf + (size_t)row * 256 + lane * 4);
        a0 = av.x; a1 = av.y; a2 = av.z; a3 = av.w;
    } else {
        uint2 av = *(const uint2*)(addb + (size_t)row * abstride + lane * 4);
        a0 = bf2f_lo(av.x); a1 = bf2f_hi(av.x);
        a2 = bf2f_lo(av.y); a3 = bf2f_hi(av.y);
    }
    ushort4 o;
    o.x = f2bf(fmaxf((v.x - mu) * rs * gv.x + bv.x, 0.f) + a0);
    o.y = f2bf(fmaxf((v.y - mu) * rs * gv.y + bv.y, 0.f) + a1);
    o.z = f2bf(fmaxf((v.z - mu) * rs * gv.z + bv.z, 0.f) + a2);
    o.w = f2bf(fmaxf((v.w - mu) * rs * gv.w + bv.w, 0.f) + a3);
    *(ushort4*)(out + (size_t)row * ostride + lane * 4) = o;
}

// ================= launch =================
extern "C" void kernel_launch(void* const* d_in, const int* in_sizes, int n_in,
                              void* d_out, int out_size, void* d_ws, size_t ws_size,
                              hipStream_t stream) {
    const float* x   = (const float*)d_in[0];
    const int*   ei  = (const int*)d_in[1];
    const float* W1l = (const float*)d_in[2];
    const float* b1l = (const float*)d_in[3];
    const float* W1r = (const float*)d_in[4];
    const float* g1  = (const float*)d_in[5];
    const float* be1 = (const float*)d_in[6];
    const float* Wsk = (const float*)d_in[7];
    const float* bsk = (const float*)d_in[8];
    const float* W2l = (const float*)d_in[9];
    const float* b2l = (const float*)d_in[10];
    const float* W2r = (const float*)d_in[11];
    const float* g2  = (const float*)d_in[12];
    const float* be2 = (const float*)d_in[13];
    const float* W3l = (const float*)d_in[14];
    const float* b3l = (const float*)d_in[15];
    const float* W3r = (const float*)d_in[16];

    const int N = in_sizes[0] / 128;
    const int E = in_sizes[1] / 2;
    const int* src = ei;
    const int* dst = ei + E;

    char* p = (char*)d_ws;
    auto alloc = [&](size_t bytes) {
        void* r = (void*)p;
        p += (bytes + 255) & ~(size_t)255;
        return r;
    };
    int*   cnt    = (int*)alloc(sizeof(int) * N);
    int*   rowptr = (int*)alloc(sizeof(int) * (N + 1));
    int*   cursor = (int*)alloc(sizeof(int) * N);
    float* invdeg = (float*)alloc(sizeof(float) * N);
    int*   col    = (int*)alloc(sizeof(int) * E);
    int*   bsum   = (int*)alloc(sizeof(int) * 256);
    int*   boff   = (int*)alloc(sizeof(int) * 256);
    unsigned short* A1cat = (unsigned short*)alloc(sizeof(short) * (size_t)N * 256);  // [agg1|x]; later t3
    unsigned short* A2cat = (unsigned short*)alloc(sizeof(short) * (size_t)N * 512);  // [agg2|h]; later [h2|h]
    float* u    = (float*)alloc(sizeof(float) * (size_t)N * 256);   // u1, u2
    float* sbuf = (float*)alloc(sizeof(float) * (size_t)N * 256);   // s; later r3
    unsigned short* Wt1 = (unsigned short*)alloc(sizeof(short) * 256 * 256);
    unsigned short* Wts = (unsigned short*)alloc(sizeof(short) * 256 * 128);
    unsigned short* Wt2 = (unsigned short*)alloc(sizeof(short) * 256 * 512);
    unsigned short* Wt3 = (unsigned short*)alloc(sizeof(short) * 256 * 256);
    unsigned short* t3 = A1cat;
    float*          r3 = sbuf;

    // ---- CSR build ----
    hipMemsetAsync(cnt, 0, sizeof(int) * N, stream);
    hist_kernel<<<(E + 255) / 256, 256, 0, stream>>>(dst, cnt, E);
    int NB = (N + SCAN_CHUNK - 1) / SCAN_CHUNK;
    scan_blocksums<<<NB, 256, 0, stream>>>(cnt, bsum, N);
    scan_bsums<<<1, 256, 0, stream>>>(bsum, boff, NB, rowptr, N, E);
    scan_final<<<NB, 256, 0, stream>>>(cnt, boff, rowptr, cursor, invdeg, N);
    scatter_kernel<<<(E + 255) / 256, 256, 0, stream>>>(src, dst, cursor, col, E);

    // ---- prep ----
    prep_weights<<<(294912 + 255) / 256, 256, 0, stream>>>(W1l, W1r, Wsk, W2l, W2r, W3l, W3r,
                                                           Wt1, Wts, Wt2, Wt3);
    cvt_x_kernel<<<((N * 128) + 255) / 256, 256, 0, stream>>>(x, A1cat, N * 128);

    int aggBlocks = (N + 3) / 4;
    int mBlocks = (N + 127) / 128;

    // ---- layer 1 ----
    agg_bf16<<<dim3(aggBlocks, 1), 256, 0, stream>>>(rowptr, col, invdeg, A1cat + 128, 256, A1cat, 256, N);
    gemm_mfma<float><<<dim3(mBlocks, 2), 256, 0, stream>>>(A1cat, 256, 256, Wt1, 256, b1l, u, 256, N);
    gemm_mfma<float><<<dim3(mBlocks, 2), 256, 0, stream>>>(A1cat + 128, 256, 128, Wts, 128, bsk, sbuf, 256, N);
    ln_fuse<<<aggBlocks, 256, 0, stream>>>(u, sbuf, nullptr, 0, g1, be1, A2cat + 256, 512, N);

    // ---- layer 2 ----
    agg_bf16<<<dim3(aggBlocks, 2), 256, 0, stream>>>(rowptr, col, invdeg, A2cat + 256, 512, A2cat, 512, N);
    gemm_mfma<float><<<dim3(mBlocks, 2), 256, 0, stream>>>(A2cat, 512, 512, Wt2, 512, b2l, u, 256, N);
    ln_fuse<<<aggBlocks, 256, 0, stream>>>(u, nullptr, A2cat + 256, 512, g2, be2, A2cat, 512, N);

    // ---- layer 3: one split GEMM -> t3 (bf16) + r3 (fp32+bias) ----
    gemm_mfma_l3<<<dim3(mBlocks, 2), 256, 0, stream>>>(A2cat, 512, 256, Wt3, 256, b3l, t3, r3, N);
    agg_final_128<<<aggBlocks, 256, 0, stream>>>(rowptr, col, invdeg, t3, r3, (float*)d_out, N);
}

// Round 5
// 467.577 us; speedup vs baseline: 2.1904x; 1.0406x over previous
//
#include <hip/hip_runtime.h>

// ---------------- problem dims (fixed by reference) ----------------
// N=50000, E=640000, DIN=128, DH=256, DOUT=128

typedef float floatx4 __attribute__((ext_vector_type(4)));
typedef short bf16x8 __attribute__((ext_vector_type(8)));

__device__ inline unsigned short f2bf(float f) {
    unsigned u = __float_as_uint(f);
    unsigned r = (u + 0x7fffu + ((u >> 16) & 1u)) >> 16;  // RNE
    return (unsigned short)r;
}
__device__ inline float bf2f_lo(unsigned v) { return __uint_as_float(v << 16); }
__device__ inline float bf2f_hi(unsigned v) { return __uint_as_float(v & 0xffff0000u); }

__device__ inline void gl_lds16(const void* g, void* l) {
    __builtin_amdgcn_global_load_lds((const __attribute__((address_space(1))) unsigned int*)g,
                                     (__attribute__((address_space(3))) unsigned int*)l,
                                     16, 0, 0);
}

// ================= CSR build =================
__global__ void hist_kernel(const int* __restrict__ dst, int* __restrict__ cnt, int E) {
    int i = blockIdx.x * blockDim.x + threadIdx.x;
    if (i < E) atomicAdd(&cnt[dst[i]], 1);
}

#define SCAN_CHUNK 2048

__global__ __launch_bounds__(256) void scan_blocksums(const int* __restrict__ cnt,
                                                      int* __restrict__ bsum, int N) {
    __shared__ int sh[256];
    int t = threadIdx.x;
    int base = blockIdx.x * SCAN_CHUNK + t * 8;
    int s = 0;
#pragma unroll
    for (int i = 0; i < 8; i++) {
        int idx = base + i;
        if (idx < N) s += cnt[idx];
    }
    sh[t] = s;
    __syncthreads();
    for (int off = 1; off < 256; off <<= 1) {
        int v = (t >= off) ? sh[t - off] : 0;
        __syncthreads();
        sh[t] += v;
        __syncthreads();
    }
    if (t == 255) bsum[blockIdx.x] = sh[255];
}

__global__ __launch_bounds__(256) void scan_bsums(const int* __restrict__ bsum,
                                                  int* __restrict__ boff, int NB,
                                                  int* __restrict__ rowptr, int N, int E) {
    __shared__ int sh[256];
    int t = threadIdx.x;
    int v = (t < NB) ? bsum[t] : 0;
    sh[t] = v;
    __syncthreads();
    for (int off = 1; off < 256; off <<= 1) {
        int u = (t >= off) ? sh[t - off] : 0;
        __syncthreads();
        sh[t] += u;
        __syncthreads();
    }
    if (t < NB) boff[t] = sh[t] - v;
    if (t == 0) rowptr[N] = E;
}

__global__ __launch_bounds__(256) void scan_final(const int* __restrict__ cnt,
                                                  const int* __restrict__ boff,
                                                  int* __restrict__ rowptr,
                                                  int* __restrict__ cursor,
                                                  float* __restrict__ invdeg, int N) {
    __shared__ int sh[256];
    int t = threadIdx.x;
    int base = blockIdx.x * SCAN_CHUNK + t * 8;
    int c[8];
    int s = 0;
#pragma unroll
    for (int i = 0; i < 8; i++) {
        int idx = base + i;
        c[i] = (idx < N) ? cnt[idx] : 0;
        s += c[i];
    }
    sh[t] = s;
    __syncthreads();
    for (int off = 1; off < 256; off <<= 1) {
        int v = (t >= off) ? sh[t - off] : 0;
        __syncthreads();
        sh[t] += v;
        __syncthreads();
    }
    int run = boff[blockIdx.x] + sh[t] - s;
#pragma unroll
    for (int i = 0; i < 8; i++) {
        int idx = base + i;
        if (idx < N) {
            rowptr[idx] = run;
            cursor[idx] = run;
            invdeg[idx] = 1.0f / (float)(c[i] > 1 ? c[i] : 1);
            run += c[i];
        }
    }
}

__global__ void scatter_kernel(const int* __restrict__ src, const int* __restrict__ dst,
                               int* __restrict__ cursor, int* __restrict__ col, int E) {
    int i = blockIdx.x * blockDim.x + threadIdx.x;
    if (i < E) {
        int p = atomicAdd(&cursor[dst[i]], 1);
        col[p] = src[i];
    }
}

// ================= fused weight prep =================
// WtC [512,256]: rows 0-255 = [W1l;W1r]^T (u), rows 256-511 = [0;Wsk]^T (s)
// Wt2 [512(=2x256),512]  ;  Wt3 [256,256]: rows 0-127 W3l^T, 128-255 W3r^T
// biasC [512] = [b1l | bsk]
__global__ void prep_weights(const float* __restrict__ W1l, const float* __restrict__ W1r,
                             const float* __restrict__ Wsk, const float* __restrict__ W2l,
                             const float* __restrict__ W2r, const float* __restrict__ W3l,
                             const float* __restrict__ W3r, const float* __restrict__ b1l,
                             const float* __restrict__ bsk,
                             unsigned short* __restrict__ WtC, unsigned short* __restrict__ Wt2,
                             unsigned short* __restrict__ Wt3, float* __restrict__ biasC) {
    int i = blockIdx.x * blockDim.x + threadIdx.x;
    if (i < 32768) {                        // W1l [128,256]
        int k = i >> 8, n = i & 255;
        WtC[n * 256 + k] = f2bf(W1l[i]);
    } else if (i < 65536) {                 // W1r
        int j = i - 32768, k = j >> 8, n = j & 255;
        WtC[n * 256 + 128 + k] = f2bf(W1r[j]);
    } else if (i < 98304) {                 // Wsk -> rows 256-511, k-half 128-255
        int j = i - 65536, k = j >> 8, n = j & 255;
        WtC[(256 + n) * 256 + 128 + k] = f2bf(Wsk[j]);
    } else if (i < 131072) {                // zero-fill rows 256-511, k-half 0-127
        int j = i - 98304, k = j >> 8, n = j & 255;
        WtC[(256 + n) * 256 + k] = 0;
    } else if (i < 196608) {                // W2l [256,256]
        int j = i - 131072, k = j >> 8, n = j & 255;
        Wt2[n * 512 + k] = f2bf(W2l[j]);
    } else if (i < 262144) {                // W2r
        int j = i - 196608, k = j >> 8, n = j & 255;
        Wt2[n * 512 + 256 + k] = f2bf(W2r[j]);
    } else if (i < 294912) {                // W3l [256,128]
        int j = i - 262144, k = j >> 7, n = j & 127;
        Wt3[n * 256 + k] = f2bf(W3l[j]);
    } else if (i < 327680) {                // W3r
        int j = i - 294912, k = j >> 7, n = j & 127;
        Wt3[(128 + n) * 256 + k] = f2bf(W3r[j]);
    } else if (i < 328192) {                // biasC [512]
        int j = i - 327680;
        biasC[j] = (j < 256) ? b1l[j] : bsk[j - 256];
    }
}

__global__ void cvt_x_kernel(const float* __restrict__ x, unsigned short* __restrict__ A1cat, int total) {
    int i = blockIdx.x * blockDim.x + threadIdx.x;
    if (i >= total) return;
    int r = i >> 7, c = i & 127;
    A1cat[(size_t)r * 256 + 128 + c] = f2bf(x[i]);
}

// ================= CSR mean aggregation v2 =================
// one wave per (node, 128-col slice). 32 lanes x 8B cover the 256B slice;
// lane>>5 selects edge parity -> 2 edges/wave-iter, unroll x4 -> 8 gathers in flight.
__global__ __launch_bounds__(256) void agg_bf16_v2(const int* __restrict__ rowptr,
                                                   const int* __restrict__ col,
                                                   const float* __restrict__ invdeg,
                                                   const unsigned short* __restrict__ X, int xstride,
                                                   unsigned short* __restrict__ out, int ostride, int N) {
    int wid = (blockIdx.x * blockDim.x + threadIdx.x) >> 6;
    int lane = threadIdx.x & 63;
    if (wid >= N) return;
    int half = lane >> 5;
    int sub = lane & 31;
    int off = blockIdx.y * 128 + sub * 4;
    const unsigned short* Xo = X + off;
    int s = rowptr[wid], e = rowptr[wid + 1];
    float a0 = 0.f, a1 = 0.f, a2 = 0.f, a3 = 0.f;
    int j = s + half;
    for (; j + 6 < e; j += 8) {
        int c0 = col[j], c1 = col[j + 2], c2 = col[j + 4], c3 = col[j + 6];
        uint2 v0 = *(const uint2*)(Xo + (size_t)c0 * xstride);
        uint2 v1 = *(const uint2*)(Xo + (size_t)c1 * xstride);
        uint2 v2 = *(const uint2*)(Xo + (size_t)c2 * xstride);
        uint2 v3 = *(const uint2*)(Xo + (size_t)c3 * xstride);
        a0 += (bf2f_lo(v0.x) + bf2f_lo(v1.x)) + (bf2f_lo(v2.x) + bf2f_lo(v3.x));
        a1 += (bf2f_hi(v0.x) + bf2f_hi(v1.x)) + (bf2f_hi(v2.x) + bf2f_hi(v3.x));
        a2 += (bf2f_lo(v0.y) + bf2f_lo(v1.y)) + (bf2f_lo(v2.y) + bf2f_lo(v3.y));
        a3 += (bf2f_hi(v0.y) + bf2f_hi(v1.y)) + (bf2f_hi(v2.y) + bf2f_hi(v3.y));
    }
    for (; j < e; j += 2) {
        int c = col[j];
        uint2 v = *(const uint2*)(Xo + (size_t)c * xstride);
        a0 += bf2f_lo(v.x); a1 += bf2f_hi(v.x);
        a2 += bf2f_lo(v.y); a3 += bf2f_hi(v.y);
    }
    a0 += __shfl_xor(a0, 32, 64);
    a1 += __shfl_xor(a1, 32, 64);
    a2 += __shfl_xor(a2, 32, 64);
    a3 += __shfl_xor(a3, 32, 64);
    if (half == 0) {
        float inv = invdeg[wid];
        ushort4 o;
        o.x = f2bf(a0 * inv); o.y = f2bf(a1 * inv);
        o.z = f2bf(a2 * inv); o.w = f2bf(a3 * inv);
        *(ushort4*)(out + (size_t)wid * ostride + off) = o;
    }
}

// final: out = mean-agg(T bf16 [N,128]) + R fp32 [N,128], fp32 out
__global__ __launch_bounds__(256) void agg_final_v2(const int* __restrict__ rowptr,
                                                    const int* __restrict__ col,
                                                    const float* __restrict__ invdeg,
                                                    const unsigned short* __restrict__ T,
                                                    const float* __restrict__ R,
                                                    float* __restrict__ out, int N) {
    int wid = (blockIdx.x * blockDim.x + threadIdx.x) >> 6;
    int lane = threadIdx.x & 63;
    if (wid >= N) return;
    int half = lane >> 5;
    int sub = lane & 31;
    const unsigned short* To = T + sub * 4;
    int s = rowptr[wid], e = rowptr[wid + 1];
    float a0 = 0.f, a1 = 0.f, a2 = 0.f, a3 = 0.f;
    int j = s + half;
    for (; j + 6 < e; j += 8) {
        int c0 = col[j], c1 = col[j + 2], c2 = col[j + 4], c3 = col[j + 6];
        uint2 v0 = *(const uint2*)(To + (size_t)c0 * 128);
        uint2 v1 = *(const uint2*)(To + (size_t)c1 * 128);
        uint2 v2 = *(const uint2*)(To + (size_t)c2 * 128);
        uint2 v3 = *(const uint2*)(To + (size_t)c3 * 128);
        a0 += (bf2f_lo(v0.x) + bf2f_lo(v1.x)) + (bf2f_lo(v2.x) + bf2f_lo(v3.x));
        a1 += (bf2f_hi(v0.x) + bf2f_hi(v1.x)) + (bf2f_hi(v2.x) + bf2f_hi(v3.x));
        a2 += (bf2f_lo(v0.y) + bf2f_lo(v1.y)) + (bf2f_lo(v2.y) + bf2f_lo(v3.y));
        a3 += (bf2f_hi(v0.y) + bf2f_hi(v1.y)) + (bf2f_hi(v2.y) + bf2f_hi(v3.y));
    }
    for (; j < e; j += 2) {
        int c = col[j];
        uint2 v = *(const uint2*)(To + (size_t)c * 128);
        a0 += bf2f_lo(v.x); a1 += bf2f_hi(v.x);
        a2 += bf2f_lo(v.y); a3 += bf2f_hi(v.y);
    }
    a0 += __shfl_xor(a0, 32, 64);
    a1 += __shfl_xor(a1, 32, 64);
    a2 += __shfl_xor(a2, 32, 64);
    a3 += __shfl_xor(a3, 32, 64);
    if (half == 0) {
        float inv = invdeg[wid];
        float4 r = *(const float4*)(R + (size_t)wid * 128 + sub * 4);
        float4 o;
        o.x = a0 * inv + r.x;
        o.y = a1 * inv + r.y;
        o.z = a2 * inv + r.z;
        o.w = a3 * inv + r.w;
        *(float4*)(out + (size_t)wid * 128 + sub * 4) = o;
    }
}

// ================= bf16 MFMA GEMM: C = A@B^T(+bias) =================
__device__ inline void store_out(float* p, float v) { *p = v; }
__device__ inline void store_out(unsigned short* p, float v) { *p = f2bf(v); }

template <typename OT>
__global__ __launch_bounds__(256) void gemm_mfma(const unsigned short* __restrict__ A, int lda, int K,
                                                 const unsigned short* __restrict__ B, int ldb,
                                                 const float* __restrict__ bias,
                                                 OT* __restrict__ C, int ldc, int M) {
    __shared__ unsigned short sA[128 * 64];  // [row][k]
    __shared__ unsigned short sB[128 * 64];  // [n][k]
    int t = threadIdx.x;
    int bm = blockIdx.x * 128;
    int bn = blockIdx.y * 128;
    int lane = t & 63;
    int w = t >> 6;
    int wm = (w >> 1) * 64, wn = (w & 1) * 64;

    floatx4 acc[4][4];
#pragma unroll
    for (int i = 0; i < 4; i++)
#pragma unroll
        for (int j = 0; j < 4; j++) acc[i][j] = (floatx4){0.f, 0.f, 0.f, 0.f};

    const int rA0 = t >> 3;
    const int kc8 = (t & 7) * 8;

    for (int k0 = 0; k0 < K; k0 += 64) {
#pragma unroll
        for (int i = 0; i < 4; i++) {
            int row = bm + rA0 + i * 32;
            if (row > M - 1) row = M - 1;
            gl_lds16(A + (size_t)row * lda + k0 + kc8, (void*)&sA[(size_t)(i * 256 + t) * 8]);
            gl_lds16(B + (size_t)(bn + rA0 + i * 32) * ldb + k0 + kc8,
                     (void*)&sB[(size_t)(i * 256 + t) * 8]);
        }
        __syncthreads();
#pragma unroll
        for (int ks = 0; ks < 2; ks++) {
            bf16x8 af[4], bfr[4];
#pragma unroll
            for (int mi = 0; mi < 4; mi++)
                af[mi] = *(const bf16x8*)&sA[(wm + mi * 16 + (lane & 15)) * 64 + ks * 32 + (lane >> 4) * 8];
#pragma unroll
            for (int ni = 0; ni < 4; ni++)
                bfr[ni] = *(const bf16x8*)&sB[(wn + ni * 16 + (lane & 15)) * 64 + ks * 32 + (lane >> 4) * 8];
#pragma unroll
            for (int mi = 0; mi < 4; mi++)
#pragma unroll
                for (int ni = 0; ni < 4; ni++)
                    acc[mi][ni] = __builtin_amdgcn_mfma_f32_16x16x32_bf16(af[mi], bfr[ni], acc[mi][ni], 0, 0, 0);
        }
        __syncthreads();
    }

    int col0 = bn + wn + (lane & 15);
    int rbase = bm + wm + (lane >> 4) * 4;
#pragma unroll
    for (int ni = 0; ni < 4; ni++) {
        int col = col0 + ni * 16;
        float bv = bias ? bias[col] : 0.f;
#pragma unroll
        for (int mi = 0; mi < 4; mi++) {
#pragma unroll
            for (int r = 0; r < 4; r++) {
                int row = rbase + mi * 16 + r;
                if (row < M) store_out(C + (size_t)row * ldc + col, acc[mi][ni][r] + bv);
            }
        }
    }
}

// L3 split-epilogue GEMM: cols 0-127 -> T bf16, cols 128-255 -> R fp32 + bias
__global__ __launch_bounds__(256) void gemm_mfma_l3(const unsigned short* __restrict__ A, int lda, int K,
                                                    const unsigned short* __restrict__ B, int ldb,
                                                    const float* __restrict__ bias,
                                                    unsigned short* __restrict__ T,
                                                    float* __restrict__ R, int M) {
    __shared__ unsigned short sA[128 * 64];
    __shared__ unsigned short sB[128 * 64];
    int t = threadIdx.x;
    int bm = blockIdx.x * 128;
    int bn = blockIdx.y * 128;
    int lane = t & 63;
    int w = t >> 6;
    int wm = (w >> 1) * 64, wn = (w & 1) * 64;

    floatx4 acc[4][4];
#pragma unroll
    for (int i = 0; i < 4; i++)
#pragma unroll
        for (int j = 0; j < 4; j++) acc[i][j] = (floatx4){0.f, 0.f, 0.f, 0.f};

    const int rA0 = t >> 3;
    const int kc8 = (t & 7) * 8;

    for (int k0 = 0; k0 < K; k0 += 64) {
#pragma unroll
        for (int i = 0; i < 4; i++) {
            int row = bm + rA0 + i * 32;
            if (row > M - 1) row = M - 1;
            gl_lds16(A + (size_t)row * lda + k0 + kc8, (void*)&sA[(size_t)(i * 256 + t) * 8]);
            gl_lds16(B + (size_t)(bn + rA0 + i * 32) * ldb + k0 + kc8,
                     (void*)&sB[(size_t)(i * 256 + t) * 8]);
        }
        __syncthreads();
#pragma unroll
        for (int ks = 0; ks < 2; ks++) {
            bf16x8 af[4], bfr[4];
#pragma unroll
            for (int mi = 0; mi < 4; mi++)
                af[mi] = *(const bf16x8*)&sA[(wm + mi * 16 + (lane & 15)) * 64 + ks * 32 + (lane >> 4) * 8];
#pragma unroll
            for (int ni = 0; ni < 4; ni++)
                bfr[ni] = *(const bf16x8*)&sB[(wn + ni * 16 + (lane & 15)) * 64 + ks * 32 + (lane >> 4) * 8];
#pragma unroll
            for (int mi = 0; mi < 4; mi++)
#pragma unroll
                for (int ni = 0; ni < 4; ni++)
                    acc[mi][ni] = __builtin_amdgcn_mfma_f32_16x16x32_bf16(af[mi], bfr[ni], acc[mi][ni], 0, 0, 0);
        }
        __syncthreads();
    }

    int col0 = bn + wn + (lane & 15);
    int rbase = bm + wm + (lane >> 4) * 4;
#pragma unroll
    for (int ni = 0; ni < 4; ni++) {
        int col = col0 + ni * 16;
        if (col < 128) {
#pragma unroll
            for (int mi = 0; mi < 4; mi++)
#pragma unroll
                for (int r = 0; r < 4; r++) {
                    int row = rbase + mi * 16 + r;
                    if (row < M) T[(size_t)row * 128 + col] = f2bf(acc[mi][ni][r]);
                }
        } else {
            float bv = bias[col - 128];
#pragma unroll
            for (int mi = 0; mi < 4; mi++)
#pragma unroll
                for (int r = 0; r < 4; r++) {
                    int row = rbase + mi * 16 + r;
                    if (row < M) R[(size_t)row * 128 + col - 128] = acc[mi][ni][r] + bv;
                }
        }
    }
}

// ================= LayerNorm(256)+ReLU+add, all-bf16 I/O =================
// u: bf16 [N, ustride] (256 cols used), addend a: bf16 [N, astride]
__global__ __launch_bounds__(256) void ln_fuse2(const unsigned short* __restrict__ u, int ustride,
                                                const unsigned short* __restrict__ a, int astride,
                                                const float* __restrict__ g, const float* __restrict__ b,
                                                unsigned short* __restrict__ out, int ostride, int N) {
    int row = (blockIdx.x * blockDim.x + threadIdx.x) >> 6;
    int lane = threadIdx.x & 63;
    if (row >= N) return;
    uint2 uv = *(const uint2*)(u + (size_t)row * ustride + lane * 4);
    float v0 = bf2f_lo(uv.x), v1 = bf2f_hi(uv.x), v2 = bf2f_lo(uv.y), v3 = bf2f_hi(uv.y);
    float s = (v0 + v1) + (v2 + v3);
    float sq = (v0 * v0 + v1 * v1) + (v2 * v2 + v3 * v3);
    for (int off = 1; off < 64; off <<= 1) {
        s += __shfl_xor(s, off, 64);
        sq += __shfl_xor(sq, off, 64);
    }
    float mu = s * (1.f / 256.f);
    float var = sq * (1.f / 256.f) - mu * mu;
    float rs = rsqrtf(var + 1e-5f);
    float4 gv = *(const float4*)(g + lane * 4);
    float4 bv = *(const float4*)(b + lane * 4);
    uint2 av = *(const uint2*)(a + (size_t)row * astride + lane * 4);
    float a0 = bf2f_lo(av.x), a1 = bf2f_hi(av.x), a2 = bf2f_lo(av.y), a3 = bf2f_hi(av.y);
    ushort4 o;
    o.x = f2bf(fmaxf((v0 - mu) * rs * gv.x + bv.x, 0.f) + a0);
    o.y = f2bf(fmaxf((v1 - mu) * rs * gv.y + bv.y, 0.f) + a1);
    o.z = f2bf(fmaxf((v2 - mu) * rs * gv.z + bv.z, 0.f) + a2);
    o.w = f2bf(fmaxf((v3 - mu) * rs * gv.w + bv.w, 0.f) + a3);
    *(ushort4*)(out + (size_t)row * ostride + lane * 4) = o;
}

// ================= launch =================
extern "C" void kernel_launch(void* const* d_in, const int* in_sizes, int n_in,
                              void* d_out, int out_size, void* d_ws, size_t ws_size,
                              hipStream_t stream) {
    const float* x   = (const float*)d_in[0];
    const int*   ei  = (const int*)d_in[1];
    const float* W1l = (const float*)d_in[2];
    const float* b1l = (const float*)d_in[3];
    const float* W1r = (const float*)d_in[4];
    const float* g1  = (const float*)d_in[5];
    const float* be1 = (const float*)d_in[6];
    const float* Wsk = (const float*)d_in[7];
    const float* bsk = (const float*)d_in[8];
    const float* W2l = (const float*)d_in[9];
    const float* b2l = (const float*)d_in[10];
    const float* W2r = (const float*)d_in[11];
    const float* g2  = (const float*)d_in[12];
    const float* be2 = (const float*)d_in[13];
    const float* W3l = (const float*)d_in[14];
    const float* b3l = (const float*)d_in[15];
    const float* W3r = (const float*)d_in[16];

    const int N = in_sizes[0] / 128;
    const int E = in_sizes[1] / 2;
    const int* src = ei;
    const int* dst = ei + E;

    char* p = (char*)d_ws;
    auto alloc = [&](size_t bytes) {
        void* r = (void*)p;
        p += (bytes + 255) & ~(size_t)255;
        return r;
    };
    int*   cnt    = (int*)alloc(sizeof(int) * N);
    int*   rowptr = (int*)alloc(sizeof(int) * (N + 1));
    int*   cursor = (int*)alloc(sizeof(int) * N);
    float* invdeg = (float*)alloc(sizeof(float) * N);
    int*   col    = (int*)alloc(sizeof(int) * E);
    int*   bsum   = (int*)alloc(sizeof(int) * 256);
    int*   boff   = (int*)alloc(sizeof(int) * 256);
    unsigned short* A1cat = (unsigned short*)alloc(sizeof(short) * (size_t)N * 256);  // [agg1|x]; later t3
    unsigned short* A2cat = (unsigned short*)alloc(sizeof(short) * (size_t)N * 512);  // [agg2|h] -> [h2|h]
    unsigned short* U1    = (unsigned short*)alloc(sizeof(short) * (size_t)N * 512);  // [u1|s] bf16; later u2
    float* r3 = (float*)alloc(sizeof(float) * (size_t)N * 128);
    unsigned short* WtC = (unsigned short*)alloc(sizeof(short) * 512 * 256);
    unsigned short* Wt2 = (unsigned short*)alloc(sizeof(short) * 256 * 512);
    unsigned short* Wt3 = (unsigned short*)alloc(sizeof(short) * 256 * 256);
    float* biasC = (float*)alloc(sizeof(float) * 512);
    unsigned short* t3 = A1cat;
    unsigned short* u2 = U1;

    // ---- CSR build ----
    hipMemsetAsync(cnt, 0, sizeof(int) * N, stream);
    hist_kernel<<<(E + 255) / 256, 256, 0, stream>>>(dst, cnt, E);
    int NB = (N + SCAN_CHUNK - 1) / SCAN_CHUNK;
    scan_blocksums<<<NB, 256, 0, stream>>>(cnt, bsum, N);
    scan_bsums<<<1, 256, 0, stream>>>(bsum, boff, NB, rowptr, N, E);
    scan_final<<<NB, 256, 0, stream>>>(cnt, boff, rowptr, cursor, invdeg, N);
    scatter_kernel<<<(E + 255) / 256, 256, 0, stream>>>(src, dst, cursor, col, E);

    // ---- prep ----
    prep_weights<<<(328192 + 255) / 256, 256, 0, stream>>>(W1l, W1r, Wsk, W2l, W2r, W3l, W3r,
                                                           b1l, bsk, WtC, Wt2, Wt3, biasC);
    cvt_x_kernel<<<((N * 128) + 255) / 256, 256, 0, stream>>>(x, A1cat, N * 128);

    int aggBlocks = (N + 3) / 4;
    int mBlocks = (N + 127) / 128;

    // ---- layer 1 ----
    agg_bf16_v2<<<dim3(aggBlocks, 1), 256, 0, stream>>>(rowptr, col, invdeg, A1cat + 128, 256, A1cat, 256, N);
    // [u1|s] = A1cat @ WtC^T + [b1l|bsk]   (N=512 output)
    gemm_mfma<unsigned short><<<dim3(mBlocks, 4), 256, 0, stream>>>(A1cat, 256, 256, WtC, 256, biasC, U1, 512, N);
    // h = relu(LN(u1)) + s -> A2cat right half
    ln_fuse2<<<aggBlocks, 256, 0, stream>>>(U1, 512, U1 + 256, 512, g1, be1, A2cat + 256, 512, N);

    // ---- layer 2 ----
    agg_bf16_v2<<<dim3(aggBlocks, 2), 256, 0, stream>>>(rowptr, col, invdeg, A2cat + 256, 512, A2cat, 512, N);
    gemm_mfma<unsigned short><<<dim3(mBlocks, 2), 256, 0, stream>>>(A2cat, 512, 512, Wt2, 512, b2l, u2, 256, N);
    // h2 = relu(LN(u2)) + h -> A2cat left half
    ln_fuse2<<<aggBlocks, 256, 0, stream>>>(u2, 256, A2cat + 256, 512, g2, be2, A2cat, 512, N);

    // ---- layer 3 ----
    gemm_mfma_l3<<<dim3(mBlocks, 2), 256, 0, stream>>>(A2cat, 512, 256, Wt3, 256, b3l, t3, r3, N);
    agg_final_v2<<<aggBlocks, 256, 0, stream>>>(rowptr, col, invdeg, t3, r3, (float*)d_out, N);
}